// Round 7
// baseline (192.105 us; speedup 1.0000x reference)
//
#include <hip/hip_runtime.h>
#include <hip/hip_bf16.h>
#include <math.h>

// Problem constants
constexpr int B_ = 4, T_ = 4096, I_ = 1024, H_ = 16, D_ = 64;
constexpr int M_ = B_ * T_;      // 16384 rows  (b*T + t)
constexpr int N_ = H_ * D_ * 2;  // 2048 cols   (h*128 + d*2 + k)
constexpr int C_ = 64;           // scan chunks
constexpr int L_ = T_ / C_;      // 64 timesteps per chunk

typedef __bf16 bf16x8 __attribute__((ext_vector_type(8)));
typedef float  f32x4  __attribute__((ext_vector_type(4)));
typedef unsigned short us8 __attribute__((ext_vector_type(8)));

__device__ __forceinline__ float silu_f(float x) {
    return x / (1.0f + __expf(-x));
}

// bf16 RNE helpers
__device__ __forceinline__ ushort f2bf_u(float x) {
    unsigned u = __float_as_uint(x);
    unsigned r = (u + 0x7fffu + ((u >> 16) & 1u)) >> 16;
    return (ushort)r;
}
__device__ __forceinline__ float bfu2f(ushort u) {
    return __uint_as_float(((unsigned)u) << 16);
}

__device__ __forceinline__ void gload_lds16(const void* g, void* l) {
    __builtin_amdgcn_global_load_lds(
        (const __attribute__((address_space(1))) unsigned int*)g,
        (__attribute__((address_space(3))) unsigned int*)l, 16, 0, 0);
}

// ---------------------------------------------------------------------------
// Conversion + transpose: Bm (1024,2048) f32 -> B2T (2048 n, 1024 k) bf16 hi
// ---------------------------------------------------------------------------
__global__ __launch_bounds__(256) void convert_bT_kernel(
    const float* __restrict__ Bm, ushort* __restrict__ B2T)
{
    __shared__ float tile[64][65];
    const int k0 = blockIdx.x * 64;
    const int n0 = blockIdx.y * 64;
    const int tid = threadIdx.x;
    #pragma unroll
    for (int p = 0; p < 4; ++p) {
        int f = tid + p * 256;
        int r  = f >> 4;
        int c4 = (f & 15) * 4;
        float4 v = *reinterpret_cast<const float4*>(
            &Bm[(size_t)(k0 + r) * 2048 + n0 + c4]);
        tile[r][c4 + 0] = v.x; tile[r][c4 + 1] = v.y;
        tile[r][c4 + 2] = v.z; tile[r][c4 + 3] = v.w;
    }
    __syncthreads();
    #pragma unroll
    for (int p = 0; p < 4; ++p) {
        int f = tid + p * 256;
        int n  = f >> 4;
        int kq = (f & 15) * 4;
        ushort4 hi;
        hi.x = f2bf_u(tile[kq + 0][n]);
        hi.y = f2bf_u(tile[kq + 1][n]);
        hi.z = f2bf_u(tile[kq + 2][n]);
        hi.w = f2bf_u(tile[kq + 3][n]);
        *reinterpret_cast<ushort4*>(&B2T[(size_t)(n0 + n) * 1024 + k0 + kq]) = hi;
    }
}

// ---------------------------------------------------------------------------
// 128x128 2-barrier MFMA GEMM (round-2 proven structure), bf16 K=1024,
// with FUSED A f32->bf16 conversion (reg-stage + ds_write, swizzled dest),
// B staged via global_load_lds with pre-swizzled source.
// Fused epilogue: silu, s = sum_d q*k, v store (bf16).
// 256 threads = 4 waves (2x2); per-wave C = 64x64; BK=64.
// ---------------------------------------------------------------------------
__global__ __launch_bounds__(256) void gemm_kv128_kernel(
    const float*  __restrict__ Af,   // (M, 1024) f32 inputs
    const ushort* __restrict__ B2T,  // (2048 n, 1024 k) bf16
    const float*  __restrict__ qk,   // (H, D)
    ushort* __restrict__ v_buf,      // (B, H, T, D) bf16
    float*  __restrict__ s_buf)      // (B, H, T)
{
    __shared__ __align__(16) ushort Asl[128 * 64];
    __shared__ __align__(16) ushort Bsl[128 * 64];
    __shared__ float spart[4][64];

    // XCD-aware swizzle: 2048 blocks, 8 XCDs -> chunks of 256
    const int bid = blockIdx.x;
    const int swz = (bid & 7) * 256 + (bid >> 3);
    const int bx  = swz & 15;        // n tile == head h
    const int by  = swz >> 4;        // m tile
    const int m0  = by * 128;
    const int n0  = bx * 128;
    const int h   = bx;

    const int tid  = threadIdx.x;
    const int lane = tid & 63;
    const int wid  = tid >> 6;
    const int wr = wid >> 1, wc = wid & 1;
    const int l15 = lane & 15, lg = lane >> 4;

    f32x4 acc[4][4];
    #pragma unroll
    for (int i = 0; i < 4; ++i)
        #pragma unroll
        for (int j = 0; j < 4; ++j)
            acc[i][j] = (f32x4){0.f, 0.f, 0.f, 0.f};

    // Staging map: chunk f (0..1023): row = f>>3, k-chunk = (f&7)^(row&7).
    // Same XOR used on the ds_read side -> conflict-free (proven r2).
    int st_row[4], st_kx[4];
    #pragma unroll
    for (int c = 0; c < 4; ++c) {
        int f = c * 256 + tid;
        st_row[c] = f >> 3;
        st_kx[c]  = ((f & 7) ^ ((f >> 3) & 7)) * 8;  // element offset
    }

    for (int k0 = 0; k0 < 1024; k0 += 64) {
        __syncthreads();
        // A: issue 8 f32 vector loads (reg-stage)
        float4 av[4][2];
        #pragma unroll
        for (int c = 0; c < 4; ++c) {
            const float* src = &Af[(size_t)(m0 + st_row[c]) * 1024 + k0 + st_kx[c]];
            av[c][0] = *reinterpret_cast<const float4*>(src);
            av[c][1] = *reinterpret_cast<const float4*>(src + 4);
        }
        // B: async global->LDS (overlaps the A-load latency)
        #pragma unroll
        for (int c = 0; c < 4; ++c) {
            int f = c * 256 + tid;
            gload_lds16(&B2T[(size_t)(n0 + st_row[c]) * 1024 + k0 + st_kx[c]],
                        &Bsl[0] + (size_t)f * 8);
        }
        // A: convert + LDS write (b128), same linear slot as r2's layout
        #pragma unroll
        for (int c = 0; c < 4; ++c) {
            int f = c * 256 + tid;
            us8 w;
            w[0] = f2bf_u(av[c][0].x); w[1] = f2bf_u(av[c][0].y);
            w[2] = f2bf_u(av[c][0].z); w[3] = f2bf_u(av[c][0].w);
            w[4] = f2bf_u(av[c][1].x); w[5] = f2bf_u(av[c][1].y);
            w[6] = f2bf_u(av[c][1].z); w[7] = f2bf_u(av[c][1].w);
            *reinterpret_cast<us8*>(&Asl[0] + (size_t)f * 8) = w;
        }
        __syncthreads();   // compiler emits vmcnt(0)+lgkmcnt(0) drain here

        #pragma unroll
        for (int kk = 0; kk < 2; ++kk) {
            bf16x8 af[4], bfv[4];
            #pragma unroll
            for (int i = 0; i < 4; ++i) {
                int ar = wr * 64 + i * 16 + l15;
                af[i] = *reinterpret_cast<const bf16x8*>(
                    &Asl[ar * 64 + ((kk * 32 + lg * 8) ^ ((ar & 7) << 3))]);
            }
            #pragma unroll
            for (int i = 0; i < 4; ++i) {
                int br = wc * 64 + i * 16 + l15;
                bfv[i] = *reinterpret_cast<const bf16x8*>(
                    &Bsl[br * 64 + ((kk * 32 + lg * 8) ^ ((br & 7) << 3))]);
            }
            #pragma unroll
            for (int i = 0; i < 4; ++i)
                #pragma unroll
                for (int j = 0; j < 4; ++j)
                    acc[i][j] = __builtin_amdgcn_mfma_f32_16x16x32_bf16(
                        af[i], bfv[j], acc[i][j], 0, 0, 0);
        }
    }

    // Epilogue (r2-proven): col n = wc*64 + j*16 + l15; even -> k, odd -> v.
    float qv[4];
    #pragma unroll
    for (int j = 0; j < 4; ++j)
        qv[j] = qk[h * 64 + wc * 32 + j * 8 + (l15 >> 1)];
    const bool kcol = ((l15 & 1) == 0);

    #pragma unroll
    for (int i = 0; i < 4; ++i) {
        #pragma unroll
        for (int r = 0; r < 4; ++r) {
            int m = m0 + wr * 64 + i * 16 + lg * 4 + r;
            int b = m >> 12, tt = m & 4095;
            float p = 0.f;
            #pragma unroll
            for (int j = 0; j < 4; ++j) {
                float sv = silu_f(acc[i][j][r]);
                if (kcol) {
                    p += qv[j] * sv;
                } else {
                    v_buf[((size_t)(b * H_ + h) * T_ + tt) * D_
                          + wc * 32 + j * 8 + (l15 >> 1)] = f2bf_u(sv);
                }
            }
            p += __shfl_xor(p, 2);
            p += __shfl_xor(p, 4);
            p += __shfl_xor(p, 8);
            if (l15 == 0) spart[wid][i * 16 + lg * 4 + r] = p;
        }
    }
    __syncthreads();
    if (tid < 128) {
        int wrr = tid >> 6, row = tid & 63;
        int m = m0 + wrr * 64 + row;
        int b = m >> 12, tt = m & 4095;
        s_buf[(size_t)(b * H_ + h) * T_ + tt] =
            spart[wrr * 2][row] + spart[wrr * 2 + 1][row];
    }
}

// ---------------------------------------------------------------------------
// Fallback f32 GEMM (round-1) used when ws_size is too small.
// ---------------------------------------------------------------------------
#define TILE_M 128
#define TILE_N 128
#define TILE_K 16
__global__ __launch_bounds__(256) void gemm_kv_kernel(
    const float* __restrict__ A, const float* __restrict__ Bm,
    const float* __restrict__ q, ushort* __restrict__ v_buf,
    float* __restrict__ s_buf)
{
    __shared__ float As[TILE_K][TILE_M + 4];
    __shared__ float Bs[TILE_K][TILE_N + 4];
    const int tid = threadIdx.x;
    const int h   = blockIdx.x;
    const int bm  = blockIdx.y;
    const int m0  = bm * TILE_M;
    const int n0  = h * TILE_N;
    const int tx = tid & 15, ty = tid >> 4;
    float acc[8][8];
    #pragma unroll
    for (int i = 0; i < 8; ++i)
        #pragma unroll
        for (int j = 0; j < 8; ++j) acc[i][j] = 0.f;
    for (int k0 = 0; k0 < I_; k0 += TILE_K) {
        #pragma unroll
        for (int p = 0; p < 2; ++p) {
            int f = tid + p * 256;
            int row = f >> 2, kq = (f & 3) * 4;
            float4 av = *reinterpret_cast<const float4*>(
                &A[(size_t)(m0 + row) * I_ + k0 + kq]);
            As[kq + 0][row] = av.x; As[kq + 1][row] = av.y;
            As[kq + 2][row] = av.z; As[kq + 3][row] = av.w;
        }
        #pragma unroll
        for (int p = 0; p < 2; ++p) {
            int f = tid + p * 256;
            int row = f >> 5, c4 = (f & 31) * 4;
            *reinterpret_cast<float4*>(&Bs[row][c4]) =
                *reinterpret_cast<const float4*>(
                    &Bm[(size_t)(k0 + row) * N_ + n0 + c4]);
        }
        __syncthreads();
        #pragma unroll
        for (int kk = 0; kk < TILE_K; ++kk) {
            float4 a0 = *reinterpret_cast<const float4*>(&As[kk][ty * 8]);
            float4 a1 = *reinterpret_cast<const float4*>(&As[kk][ty * 8 + 4]);
            float4 b0 = *reinterpret_cast<const float4*>(&Bs[kk][tx * 8]);
            float4 b1 = *reinterpret_cast<const float4*>(&Bs[kk][tx * 8 + 4]);
            float af[8] = {a0.x, a0.y, a0.z, a0.w, a1.x, a1.y, a1.z, a1.w};
            float bf[8] = {b0.x, b0.y, b0.z, b0.w, b1.x, b1.y, b1.z, b1.w};
            #pragma unroll
            for (int i = 0; i < 8; ++i)
                #pragma unroll
                for (int j = 0; j < 8; ++j)
                    acc[i][j] = fmaf(af[i], bf[j], acc[i][j]);
        }
        __syncthreads();
    }
    float4 qv = *reinterpret_cast<const float4*>(&q[h * D_ + tx * 4]);
    float qf[4] = {qv.x, qv.y, qv.z, qv.w};
    #pragma unroll
    for (int i = 0; i < 8; ++i) {
        int m = m0 + ty * 8 + i;
        int b = m >> 12, t = m & 4095;
        float partial = 0.f;
        #pragma unroll
        for (int j = 0; j < 4; ++j) {
            float kval = silu_f(acc[i][2 * j]);
            float vv = silu_f(acc[i][2 * j + 1]);
            v_buf[((size_t)(b * H_ + h) * T_ + t) * D_ + tx * 4 + j] = f2bf_u(vv);
            partial = fmaf(qf[j], kval, partial);
        }
        #pragma unroll
        for (int mask = 8; mask >= 1; mask >>= 1)
            partial += __shfl_xor(partial, mask, 16);
        if (tx == 0) s_buf[(size_t)(b * H_ + h) * T_ + t] = partial;
    }
}

// ---------------------------------------------------------------------------
// Scan kernels (v_buf bf16)
// ---------------------------------------------------------------------------
__global__ __launch_bounds__(64) void chunk_agg_kernel(
    const float* __restrict__ s_buf, const ushort* __restrict__ v_buf,
    float* __restrict__ agg_m, float* __restrict__ agg_u,
    float* __restrict__ agg_w)
{
    const int x    = blockIdx.x;
    const int c    = x & (C_ - 1);
    const int bh   = x >> 6;
    const int lane = threadIdx.x;
    const float* sp  = s_buf + (size_t)bh * T_ + c * L_;
    const ushort* vp = v_buf + ((size_t)bh * T_ + c * L_) * D_ + lane;
    float m = -INFINITY, u = 0.f, w = 0.f;
    for (int t = 0; t < L_; ++t) {
        float s  = sp[t];
        float vv = bfu2f(vp[(size_t)t * D_]);
        float mn = fmaxf(m, s);
        float ea = __expf(m - mn);
        float eb = __expf(s - mn);
        u = u * ea + eb;
        w = w * ea + vv * eb;
        m = mn;
    }
    if (lane == 0) { agg_m[x] = m; agg_u[x] = u; }
    agg_w[(size_t)x * D_ + lane] = w;
}

__global__ __launch_bounds__(64) void chunk_prefix_kernel(
    float* __restrict__ agg_m, float* __restrict__ agg_u,
    float* __restrict__ agg_w)
{
    const int bh   = blockIdx.x;
    const int lane = threadIdx.x;
    float pm = -INFINITY, pu = 0.f, pw = 0.f;
    for (int c = 0; c < C_; ++c) {
        int base = bh * C_ + c;
        float am = agg_m[base];
        float au = agg_u[base];
        float aw = agg_w[(size_t)base * D_ + lane];
        if (lane == 0) { agg_m[base] = pm; agg_u[base] = pu; }
        agg_w[(size_t)base * D_ + lane] = pw;
        float mn = fmaxf(pm, am);
        float ea = __expf(pm - mn);
        float eb = __expf(am - mn);
        pu = pu * ea + au * eb;
        pw = pw * ea + aw * eb;
        pm = mn;
    }
}

__global__ __launch_bounds__(256) void scan_apply_kernel(
    const float* __restrict__ s_buf, const ushort* __restrict__ v_buf,
    const float* __restrict__ agg_m, const float* __restrict__ agg_u,
    const float* __restrict__ agg_w, float* __restrict__ out)
{
    __shared__ float part[4][8][64];
    const int bx   = blockIdx.x;
    const int b    = bx >> 6;
    const int c    = bx & (C_ - 1);
    const int w    = threadIdx.x >> 6;
    const int lane = threadIdx.x & 63;
    float m[4], u[4], ws[4];
    #pragma unroll
    for (int j = 0; j < 4; ++j) {
        int h = w * 4 + j;
        int base = (b * H_ + h) * C_ + c;
        m[j]  = agg_m[base];
        u[j]  = agg_u[base];
        ws[j] = agg_w[(size_t)base * D_ + lane];
    }
    const int t0 = c * L_;
    for (int g = 0; g < L_ / 8; ++g) {
        #pragma unroll
        for (int qq = 0; qq < 8; ++qq) {
            int t = t0 + g * 8 + qq;
            float acc = 0.f;
            #pragma unroll
            for (int j = 0; j < 4; ++j) {
                int h = w * 4 + j;
                size_t bht = (size_t)(b * H_ + h) * T_ + t;
                float s  = s_buf[bht];
                float vv = bfu2f(v_buf[bht * D_ + lane]);
                float mn = fmaxf(m[j], s);
                float ea = __expf(m[j] - mn);
                float eb = __expf(s - mn);
                u[j]  = u[j] * ea + eb;
                ws[j] = ws[j] * ea + vv * eb;
                m[j]  = mn;
                acc += ws[j] / u[j];
            }
            part[w][qq][lane] = acc;
        }
        __syncthreads();
        {
            int e  = threadIdx.x;
            int tt = e >> 6, d = e & 63;
            float sum = part[0][tt][d] + part[1][tt][d]
                      + part[2][tt][d] + part[3][tt][d];
            out[((size_t)b * T_ + (t0 + g * 8 + tt)) * D_ + d] = sum * (1.f / 16.f);
        }
        {
            int e  = threadIdx.x + 256;
            int tt = e >> 6, d = e & 63;
            float sum = part[0][tt][d] + part[1][tt][d]
                      + part[2][tt][d] + part[3][tt][d];
            out[((size_t)b * T_ + (t0 + g * 8 + tt)) * D_ + d] = sum * (1.f / 16.f);
        }
        __syncthreads();
    }
}

// ---------------------------------------------------------------------------
extern "C" void kernel_launch(void* const* d_in, const int* in_sizes, int n_in,
                              void* d_out, int out_size, void* d_ws, size_t ws_size,
                              hipStream_t stream) {
    const float* A  = (const float*)d_in[0];  // inputs (B,T,I)
    const float* Bm = (const float*)d_in[1];  // kv_kernel (I,H,D,2)
    const float* q  = (const float*)d_in[2];  // q_kernel (H,D)
    float* out = (float*)d_out;

    // workspace layout: v (bf16) | s | agg_m | agg_u | agg_w | B2T
    ushort* v_buf = (ushort*)d_ws;                               // 16,777,216 us
    float*  s_buf = (float*)(v_buf + (size_t)B_ * H_ * T_ * D_);
    float*  agg_m = s_buf + (size_t)B_ * H_ * T_;                // 262,144 f
    float*  agg_u = agg_m + B_ * H_ * C_;
    float*  agg_w = agg_u + B_ * H_ * C_;
    ushort* B2T   = (ushort*)(agg_w + (size_t)B_ * H_ * C_ * D_);

    size_t need = (size_t)B_ * H_ * T_ * D_ * 2
                + ((size_t)262144 + 4096 + 4096 + 262144) * 4
                + (size_t)2048 * 1024 * 2;

    if (ws_size >= need) {
        convert_bT_kernel<<<dim3(16, 32), 256, 0, stream>>>(Bm, B2T);
        gemm_kv128_kernel<<<2048, 256, 0, stream>>>(A, B2T, q, v_buf, s_buf);
    } else {
        dim3 ggrid(H_, M_ / TILE_M);
        gemm_kv_kernel<<<ggrid, 256, 0, stream>>>(A, Bm, q, v_buf, s_buf);
    }
    chunk_agg_kernel<<<B_ * H_ * C_, 64, 0, stream>>>(s_buf, v_buf, agg_m, agg_u, agg_w);
    chunk_prefix_kernel<<<B_ * H_, 64, 0, stream>>>(agg_m, agg_u, agg_w);
    scan_apply_kernel<<<B_ * C_, 256, 0, stream>>>(s_buf, v_buf, agg_m, agg_u, agg_w, out);
}

// Round 8
// 177.133 us; speedup vs baseline: 1.0845x; 1.0845x over previous
//
#include <hip/hip_runtime.h>
#include <hip/hip_bf16.h>
#include <math.h>

// Problem constants
constexpr int B_ = 4, T_ = 4096, I_ = 1024, H_ = 16, D_ = 64;
constexpr int M_ = B_ * T_;      // 16384 rows  (b*T + t)
constexpr int N_ = H_ * D_ * 2;  // 2048 cols   (h*128 + d*2 + k)
constexpr int C_ = 64;           // scan chunks
constexpr int L_ = T_ / C_;      // 64 timesteps per chunk

typedef __bf16 bf16x8 __attribute__((ext_vector_type(8)));
typedef float  f32x4  __attribute__((ext_vector_type(4)));

__device__ __forceinline__ float silu_f(float x) {
    return x / (1.0f + __expf(-x));
}

// bf16 RNE helpers
__device__ __forceinline__ ushort f2bf_u(float x) {
    unsigned u = __float_as_uint(x);
    unsigned r = (u + 0x7fffu + ((u >> 16) & 1u)) >> 16;
    return (ushort)r;
}
__device__ __forceinline__ float bfu2f(ushort u) {
    return __uint_as_float(((unsigned)u) << 16);
}

__device__ __forceinline__ void gload_lds16(const void* g, void* l) {
    __builtin_amdgcn_global_load_lds(
        (const __attribute__((address_space(1))) unsigned int*)g,
        (__attribute__((address_space(3))) unsigned int*)l, 16, 0, 0);
}

// ---------------------------------------------------------------------------
// Conversion: A (M,1024) f32 -> A2 (M,1024) bf16 (hi only)  [R6-proven]
// ---------------------------------------------------------------------------
__global__ __launch_bounds__(256) void convert_a_kernel(
    const float* __restrict__ A, ushort* __restrict__ A2)
{
    int idx = blockIdx.x * 256 + threadIdx.x;
    int m  = idx >> 8;
    int kq = (idx & 255) * 4;
    float4 a = *reinterpret_cast<const float4*>(&A[(size_t)m * 1024 + kq]);
    ushort4 hi;
    hi.x = f2bf_u(a.x);
    hi.y = f2bf_u(a.y);
    hi.z = f2bf_u(a.z);
    hi.w = f2bf_u(a.w);
    *reinterpret_cast<ushort4*>(&A2[(size_t)m * 1024 + kq]) = hi;
}

// ---------------------------------------------------------------------------
// Conversion + transpose: Bm (1024,2048) f32 -> B2T (2048 n, 1024 k) bf16 hi
// ---------------------------------------------------------------------------
__global__ __launch_bounds__(256) void convert_bT_kernel(
    const float* __restrict__ Bm, ushort* __restrict__ B2T)
{
    __shared__ float tile[64][65];
    const int k0 = blockIdx.x * 64;
    const int n0 = blockIdx.y * 64;
    const int tid = threadIdx.x;
    #pragma unroll
    for (int p = 0; p < 4; ++p) {
        int f = tid + p * 256;
        int r  = f >> 4;
        int c4 = (f & 15) * 4;
        float4 v = *reinterpret_cast<const float4*>(
            &Bm[(size_t)(k0 + r) * 2048 + n0 + c4]);
        tile[r][c4 + 0] = v.x; tile[r][c4 + 1] = v.y;
        tile[r][c4 + 2] = v.z; tile[r][c4 + 3] = v.w;
    }
    __syncthreads();
    #pragma unroll
    for (int p = 0; p < 4; ++p) {
        int f = tid + p * 256;
        int n  = f >> 4;
        int kq = (f & 15) * 4;
        ushort4 hi;
        hi.x = f2bf_u(tile[kq + 0][n]);
        hi.y = f2bf_u(tile[kq + 1][n]);
        hi.z = f2bf_u(tile[kq + 2][n]);
        hi.w = f2bf_u(tile[kq + 3][n]);
        *reinterpret_cast<ushort4*>(&B2T[(size_t)(n0 + n) * 1024 + k0 + kq]) = hi;
    }
}

// ---------------------------------------------------------------------------
// 128x128 2-barrier MFMA GEMM (R2-proven structure), bf16 K=1024.
// Both A2 and B2T staged via global_load_lds (pre-swizzled source, linear
// LDS dest, swizzled ds_read -> 0 bank conflicts).
// Fused epilogue: silu, s = sum_d q*k, v store (bf16).
// 256 threads = 4 waves (2x2); per-wave C = 64x64; BK=64.
// ---------------------------------------------------------------------------
__global__ __launch_bounds__(256) void gemm_kv128_kernel(
    const ushort* __restrict__ A2,   // (M, 1024) bf16
    const ushort* __restrict__ B2T,  // (2048 n, 1024 k) bf16
    const float*  __restrict__ qk,   // (H, D)
    ushort* __restrict__ v_buf,      // (B, H, T, D) bf16
    float*  __restrict__ s_buf)      // (B, H, T)
{
    __shared__ __align__(16) ushort Asl[128 * 64];
    __shared__ __align__(16) ushort Bsl[128 * 64];
    __shared__ float spart[4][64];

    // XCD-aware swizzle: 2048 blocks, 8 XCDs -> chunks of 256
    const int bid = blockIdx.x;
    const int swz = (bid & 7) * 256 + (bid >> 3);
    const int bx  = swz & 15;        // n tile == head h
    const int by  = swz >> 4;        // m tile
    const int m0  = by * 128;
    const int n0  = bx * 128;
    const int h   = bx;

    const int tid  = threadIdx.x;
    const int lane = tid & 63;
    const int wid  = tid >> 6;
    const int wr = wid >> 1, wc = wid & 1;
    const int l15 = lane & 15, lg = lane >> 4;

    f32x4 acc[4][4];
    #pragma unroll
    for (int i = 0; i < 4; ++i)
        #pragma unroll
        for (int j = 0; j < 4; ++j)
            acc[i][j] = (f32x4){0.f, 0.f, 0.f, 0.f};

    // Staging map: chunk f (0..1023): row = f>>3, k-chunk = (f&7)^(row&7).
    int st_row[4], st_kx[4];
    #pragma unroll
    for (int c = 0; c < 4; ++c) {
        int f = c * 256 + tid;
        st_row[c] = f >> 3;
        st_kx[c]  = ((f & 7) ^ ((f >> 3) & 7)) * 8;  // ushort offset
    }

    for (int k0 = 0; k0 < 1024; k0 += 64) {
        __syncthreads();
        #pragma unroll
        for (int c = 0; c < 4; ++c) {
            int f = c * 256 + tid;
            gload_lds16(&A2[(size_t)(m0 + st_row[c]) * 1024 + k0 + st_kx[c]],
                        &Asl[0] + (size_t)f * 8);
        }
        #pragma unroll
        for (int c = 0; c < 4; ++c) {
            int f = c * 256 + tid;
            gload_lds16(&B2T[(size_t)(n0 + st_row[c]) * 1024 + k0 + st_kx[c]],
                        &Bsl[0] + (size_t)f * 8);
        }
        __syncthreads();

        #pragma unroll
        for (int kk = 0; kk < 2; ++kk) {
            bf16x8 af[4], bfv[4];
            #pragma unroll
            for (int i = 0; i < 4; ++i) {
                int ar = wr * 64 + i * 16 + l15;
                af[i] = *reinterpret_cast<const bf16x8*>(
                    &Asl[ar * 64 + ((kk * 32 + lg * 8) ^ ((ar & 7) << 3))]);
            }
            #pragma unroll
            for (int i = 0; i < 4; ++i) {
                int br = wc * 64 + i * 16 + l15;
                bfv[i] = *reinterpret_cast<const bf16x8*>(
                    &Bsl[br * 64 + ((kk * 32 + lg * 8) ^ ((br & 7) << 3))]);
            }
            #pragma unroll
            for (int i = 0; i < 4; ++i)
                #pragma unroll
                for (int j = 0; j < 4; ++j)
                    acc[i][j] = __builtin_amdgcn_mfma_f32_16x16x32_bf16(
                        af[i], bfv[j], acc[i][j], 0, 0, 0);
        }
    }

    // Epilogue: col n = wc*64 + j*16 + l15; even -> k, odd -> v; d = n>>1.
    float qv[4];
    #pragma unroll
    for (int j = 0; j < 4; ++j)
        qv[j] = qk[h * 64 + wc * 32 + j * 8 + (l15 >> 1)];
    const bool kcol = ((l15 & 1) == 0);

    #pragma unroll
    for (int i = 0; i < 4; ++i) {
        #pragma unroll
        for (int r = 0; r < 4; ++r) {
            int m = m0 + wr * 64 + i * 16 + lg * 4 + r;
            int b = m >> 12, tt = m & 4095;
            float p = 0.f;
            #pragma unroll
            for (int j = 0; j < 4; ++j) {
                float sv = silu_f(acc[i][j][r]);
                if (kcol) {
                    p += qv[j] * sv;
                } else {
                    v_buf[((size_t)(b * H_ + h) * T_ + tt) * D_
                          + wc * 32 + j * 8 + (l15 >> 1)] = f2bf_u(sv);
                }
            }
            p += __shfl_xor(p, 2);
            p += __shfl_xor(p, 4);
            p += __shfl_xor(p, 8);
            if (l15 == 0) spart[wid][i * 16 + lg * 4 + r] = p;
        }
    }
    __syncthreads();
    if (tid < 128) {
        int wrr = tid >> 6, row = tid & 63;
        int m = m0 + wrr * 64 + row;
        int b = m >> 12, tt = m & 4095;
        s_buf[(size_t)(b * H_ + h) * T_ + tt] =
            spart[wrr * 2][row] + spart[wrr * 2 + 1][row];
    }
}

// ---------------------------------------------------------------------------
// Fallback f32 GEMM (round-1) used when ws_size is too small.
// ---------------------------------------------------------------------------
#define TILE_M 128
#define TILE_N 128
#define TILE_K 16
__global__ __launch_bounds__(256) void gemm_kv_kernel(
    const float* __restrict__ A, const float* __restrict__ Bm,
    const float* __restrict__ q, ushort* __restrict__ v_buf,
    float* __restrict__ s_buf)
{
    __shared__ float As[TILE_K][TILE_M + 4];
    __shared__ float Bs[TILE_K][TILE_N + 4];
    const int tid = threadIdx.x;
    const int h   = blockIdx.x;
    const int bm  = blockIdx.y;
    const int m0  = bm * TILE_M;
    const int n0  = h * TILE_N;
    const int tx = tid & 15, ty = tid >> 4;
    float acc[8][8];
    #pragma unroll
    for (int i = 0; i < 8; ++i)
        #pragma unroll
        for (int j = 0; j < 8; ++j) acc[i][j] = 0.f;
    for (int k0 = 0; k0 < I_; k0 += TILE_K) {
        #pragma unroll
        for (int p = 0; p < 2; ++p) {
            int f = tid + p * 256;
            int row = f >> 2, kq = (f & 3) * 4;
            float4 av = *reinterpret_cast<const float4*>(
                &A[(size_t)(m0 + row) * I_ + k0 + kq]);
            As[kq + 0][row] = av.x; As[kq + 1][row] = av.y;
            As[kq + 2][row] = av.z; As[kq + 3][row] = av.w;
        }
        #pragma unroll
        for (int p = 0; p < 2; ++p) {
            int f = tid + p * 256;
            int row = f >> 5, c4 = (f & 31) * 4;
            *reinterpret_cast<float4*>(&Bs[row][c4]) =
                *reinterpret_cast<const float4*>(
                    &Bm[(size_t)(k0 + row) * N_ + n0 + c4]);
        }
        __syncthreads();
        #pragma unroll
        for (int kk = 0; kk < TILE_K; ++kk) {
            float4 a0 = *reinterpret_cast<const float4*>(&As[kk][ty * 8]);
            float4 a1 = *reinterpret_cast<const float4*>(&As[kk][ty * 8 + 4]);
            float4 b0 = *reinterpret_cast<const float4*>(&Bs[kk][tx * 8]);
            float4 b1 = *reinterpret_cast<const float4*>(&Bs[kk][tx * 8 + 4]);
            float af[8] = {a0.x, a0.y, a0.z, a0.w, a1.x, a1.y, a1.z, a1.w};
            float bf[8] = {b0.x, b0.y, b0.z, b0.w, b1.x, b1.y, b1.z, b1.w};
            #pragma unroll
            for (int i = 0; i < 8; ++i)
                #pragma unroll
                for (int j = 0; j < 8; ++j)
                    acc[i][j] = fmaf(af[i], bf[j], acc[i][j]);
        }
        __syncthreads();
    }
    float4 qv = *reinterpret_cast<const float4*>(&q[h * D_ + tx * 4]);
    float qf[4] = {qv.x, qv.y, qv.z, qv.w};
    #pragma unroll
    for (int i = 0; i < 8; ++i) {
        int m = m0 + ty * 8 + i;
        int b = m >> 12, t = m & 4095;
        float partial = 0.f;
        #pragma unroll
        for (int j = 0; j < 4; ++j) {
            float kval = silu_f(acc[i][2 * j]);
            float vv = silu_f(acc[i][2 * j + 1]);
            v_buf[((size_t)(b * H_ + h) * T_ + t) * D_ + tx * 4 + j] = f2bf_u(vv);
            partial = fmaf(qf[j], kval, partial);
        }
        #pragma unroll
        for (int mask = 8; mask >= 1; mask >>= 1)
            partial += __shfl_xor(partial, mask, 16);
        if (tx == 0) s_buf[(size_t)(b * H_ + h) * T_ + t] = partial;
    }
}

// ---------------------------------------------------------------------------
// Scan kernels (v_buf bf16)
// ---------------------------------------------------------------------------
__global__ __launch_bounds__(64) void chunk_agg_kernel(
    const float* __restrict__ s_buf, const ushort* __restrict__ v_buf,
    float* __restrict__ agg_m, float* __restrict__ agg_u,
    float* __restrict__ agg_w)
{
    const int x    = blockIdx.x;
    const int c    = x & (C_ - 1);
    const int bh   = x >> 6;
    const int lane = threadIdx.x;
    const float* sp  = s_buf + (size_t)bh * T_ + c * L_;
    const ushort* vp = v_buf + ((size_t)bh * T_ + c * L_) * D_ + lane;
    float m = -INFINITY, u = 0.f, w = 0.f;
    for (int t = 0; t < L_; ++t) {
        float s  = sp[t];
        float vv = bfu2f(vp[(size_t)t * D_]);
        float mn = fmaxf(m, s);
        float ea = __expf(m - mn);
        float eb = __expf(s - mn);
        u = u * ea + eb;
        w = w * ea + vv * eb;
        m = mn;
    }
    if (lane == 0) { agg_m[x] = m; agg_u[x] = u; }
    agg_w[(size_t)x * D_ + lane] = w;
}

__global__ __launch_bounds__(64) void chunk_prefix_kernel(
    float* __restrict__ agg_m, float* __restrict__ agg_u,
    float* __restrict__ agg_w)
{
    const int bh   = blockIdx.x;
    const int lane = threadIdx.x;
    float pm = -INFINITY, pu = 0.f, pw = 0.f;
    for (int c = 0; c < C_; ++c) {
        int base = bh * C_ + c;
        float am = agg_m[base];
        float au = agg_u[base];
        float aw = agg_w[(size_t)base * D_ + lane];
        if (lane == 0) { agg_m[base] = pm; agg_u[base] = pu; }
        agg_w[(size_t)base * D_ + lane] = pw;
        float mn = fmaxf(pm, am);
        float ea = __expf(pm - mn);
        float eb = __expf(am - mn);
        pu = pu * ea + au * eb;
        pw = pw * ea + aw * eb;
        pm = mn;
    }
}

__global__ __launch_bounds__(256) void scan_apply_kernel(
    const float* __restrict__ s_buf, const ushort* __restrict__ v_buf,
    const float* __restrict__ agg_m, const float* __restrict__ agg_u,
    const float* __restrict__ agg_w, float* __restrict__ out)
{
    __shared__ float part[4][8][64];
    const int bx   = blockIdx.x;
    const int b    = bx >> 6;
    const int c    = bx & (C_ - 1);
    const int w    = threadIdx.x >> 6;
    const int lane = threadIdx.x & 63;
    float m[4], u[4], ws[4];
    #pragma unroll
    for (int j = 0; j < 4; ++j) {
        int h = w * 4 + j;
        int base = (b * H_ + h) * C_ + c;
        m[j]  = agg_m[base];
        u[j]  = agg_u[base];
        ws[j] = agg_w[(size_t)base * D_ + lane];
    }
    const int t0 = c * L_;
    for (int g = 0; g < L_ / 8; ++g) {
        #pragma unroll
        for (int qq = 0; qq < 8; ++qq) {
            int t = t0 + g * 8 + qq;
            float acc = 0.f;
            #pragma unroll
            for (int j = 0; j < 4; ++j) {
                int h = w * 4 + j;
                size_t bht = (size_t)(b * H_ + h) * T_ + t;
                float s  = s_buf[bht];
                float vv = bfu2f(v_buf[bht * D_ + lane]);
                float mn = fmaxf(m[j], s);
                float ea = __expf(m[j] - mn);
                float eb = __expf(s - mn);
                u[j]  = u[j] * ea + eb;
                ws[j] = ws[j] * ea + vv * eb;
                m[j]  = mn;
                acc += ws[j] / u[j];
            }
            part[w][qq][lane] = acc;
        }
        __syncthreads();
        {
            int e  = threadIdx.x;
            int tt = e >> 6, d = e & 63;
            float sum = part[0][tt][d] + part[1][tt][d]
                      + part[2][tt][d] + part[3][tt][d];
            out[((size_t)b * T_ + (t0 + g * 8 + tt)) * D_ + d] = sum * (1.f / 16.f);
        }
        {
            int e  = threadIdx.x + 256;
            int tt = e >> 6, d = e & 63;
            float sum = part[0][tt][d] + part[1][tt][d]
                      + part[2][tt][d] + part[3][tt][d];
            out[((size_t)b * T_ + (t0 + g * 8 + tt)) * D_ + d] = sum * (1.f / 16.f);
        }
        __syncthreads();
    }
}

// ---------------------------------------------------------------------------
extern "C" void kernel_launch(void* const* d_in, const int* in_sizes, int n_in,
                              void* d_out, int out_size, void* d_ws, size_t ws_size,
                              hipStream_t stream) {
    const float* A  = (const float*)d_in[0];  // inputs (B,T,I)
    const float* Bm = (const float*)d_in[1];  // kv_kernel (I,H,D,2)
    const float* q  = (const float*)d_in[2];  // q_kernel (H,D)
    float* out = (float*)d_out;

    // workspace layout: v (bf16) | s | agg_m | agg_u | agg_w | A2 | B2T
    ushort* v_buf = (ushort*)d_ws;                               // 16,777,216 us
    float*  s_buf = (float*)(v_buf + (size_t)B_ * H_ * T_ * D_);
    float*  agg_m = s_buf + (size_t)B_ * H_ * T_;                // 262,144 f
    float*  agg_u = agg_m + B_ * H_ * C_;
    float*  agg_w = agg_u + B_ * H_ * C_;
    ushort* A2    = (ushort*)(agg_w + (size_t)B_ * H_ * C_ * D_);
    ushort* B2T   = A2 + (size_t)M_ * 1024;

    size_t need = (size_t)B_ * H_ * T_ * D_ * 2
                + ((size_t)262144 + 4096 + 4096 + 262144) * 4
                + ((size_t)M_ * 1024 + (size_t)2048 * 1024) * 2;

    if (ws_size >= need) {
        convert_a_kernel<<<M_ * 1024 / (256 * 4), 256, 0, stream>>>(A, A2);
        convert_bT_kernel<<<dim3(16, 32), 256, 0, stream>>>(Bm, B2T);
        gemm_kv128_kernel<<<2048, 256, 0, stream>>>(A2, B2T, q, v_buf, s_buf);
    } else {
        dim3 ggrid(H_, M_ / TILE_M);
        gemm_kv_kernel<<<ggrid, 256, 0, stream>>>(A, Bm, q, v_buf, s_buf);
    }
    chunk_agg_kernel<<<B_ * H_ * C_, 64, 0, stream>>>(s_buf, v_buf, agg_m, agg_u, agg_w);
    chunk_prefix_kernel<<<B_ * H_, 64, 0, stream>>>(agg_m, agg_u, agg_w);
    scan_apply_kernel<<<B_ * C_, 256, 0, stream>>>(s_buf, v_buf, agg_m, agg_u, agg_w, out);
}

// Round 9
// 165.929 us; speedup vs baseline: 1.1578x; 1.0675x over previous
//
#include <hip/hip_runtime.h>
#include <hip/hip_bf16.h>
#include <math.h>

// Problem constants
constexpr int B_ = 4, T_ = 4096, I_ = 1024, H_ = 16, D_ = 64;
constexpr int M_ = B_ * T_;      // 16384 rows  (b*T + t)
constexpr int N_ = H_ * D_ * 2;  // 2048 cols   (h*128 + d*2 + k)
constexpr int C_ = 64;           // scan chunks
constexpr int L_ = T_ / C_;      // 64 timesteps per chunk
constexpr int NT_ = 16;          // K-tiles: plain bf16, K=1024

typedef __bf16 bf16x8 __attribute__((ext_vector_type(8)));
typedef float  f32x4  __attribute__((ext_vector_type(4)));

__device__ __forceinline__ float silu_f(float x) {
    return x / (1.0f + __expf(-x));
}

// bf16 RNE helpers
__device__ __forceinline__ ushort f2bf_u(float x) {
    unsigned u = __float_as_uint(x);
    unsigned r = (u + 0x7fffu + ((u >> 16) & 1u)) >> 16;
    return (ushort)r;
}
__device__ __forceinline__ float bfu2f(ushort u) {
    return __uint_as_float(((unsigned)u) << 16);
}

__device__ __forceinline__ void gload_lds16(const void* g, void* l) {
    __builtin_amdgcn_global_load_lds(
        (const __attribute__((address_space(1))) unsigned int*)g,
        (__attribute__((address_space(3))) unsigned int*)l, 16, 0, 0);
}

// ---------------------------------------------------------------------------
// Conversion: A (M,1024) f32 -> A2 (M,1024) bf16 (hi only)
// ---------------------------------------------------------------------------
__global__ __launch_bounds__(256) void convert_a_kernel(
    const float* __restrict__ A, ushort* __restrict__ A2)
{
    int idx = blockIdx.x * 256 + threadIdx.x;
    int m  = idx >> 8;
    int kq = (idx & 255) * 4;
    float4 a = *reinterpret_cast<const float4*>(&A[(size_t)m * 1024 + kq]);
    ushort4 hi;
    hi.x = f2bf_u(a.x);
    hi.y = f2bf_u(a.y);
    hi.z = f2bf_u(a.z);
    hi.w = f2bf_u(a.w);
    *reinterpret_cast<ushort4*>(&A2[(size_t)m * 1024 + kq]) = hi;
}

// ---------------------------------------------------------------------------
// Conversion + transpose: Bm (1024,2048) f32 -> B2T (2048 n, 1024 k) bf16 hi
// ---------------------------------------------------------------------------
__global__ __launch_bounds__(256) void convert_bT_kernel(
    const float* __restrict__ Bm, ushort* __restrict__ B2T)
{
    __shared__ float tile[64][65];
    const int k0 = blockIdx.x * 64;
    const int n0 = blockIdx.y * 64;
    const int tid = threadIdx.x;
    #pragma unroll
    for (int p = 0; p < 4; ++p) {
        int f = tid + p * 256;
        int r  = f >> 4;
        int c4 = (f & 15) * 4;
        float4 v = *reinterpret_cast<const float4*>(
            &Bm[(size_t)(k0 + r) * 2048 + n0 + c4]);
        tile[r][c4 + 0] = v.x; tile[r][c4 + 1] = v.y;
        tile[r][c4 + 2] = v.z; tile[r][c4 + 3] = v.w;
    }
    __syncthreads();
    #pragma unroll
    for (int p = 0; p < 4; ++p) {
        int f = tid + p * 256;
        int n  = f >> 4;
        int kq = (f & 15) * 4;
        ushort4 hi;
        hi.x = f2bf_u(tile[kq + 0][n]);
        hi.y = f2bf_u(tile[kq + 1][n]);
        hi.z = f2bf_u(tile[kq + 2][n]);
        hi.w = f2bf_u(tile[kq + 3][n]);
        *reinterpret_cast<ushort4*>(&B2T[(size_t)(n0 + n) * 1024 + k0 + kq]) = hi;
    }
}

// ---------------------------------------------------------------------------
// 256x256 8-phase MFMA GEMM, plain bf16 (K=1024), TWO output tiles per block
// (same n-panel; tile-1 prologue hidden under tile-0 epilogue).
// Fused epilogue: silu, s = sum_d q*k, v store (bf16).
// 512 threads = 8 waves (2M x 4N); per-wave C = 128x64; BK=64; LDS 128KB dbuf.
// Grid 256 = 1 block/CU, single round.
// ---------------------------------------------------------------------------
__device__ __forceinline__ int akof(int t) { return t * 64; }
__device__ __forceinline__ int bkof(int t) { return t * 64; }

#define BARRIER do { asm volatile("" ::: "memory"); \
    __builtin_amdgcn_s_barrier(); \
    asm volatile("" ::: "memory"); } while (0)
#define WAITLGKM asm volatile("s_waitcnt lgkmcnt(0)" ::: "memory")
#define WAITVM(n) asm volatile("s_waitcnt vmcnt(" #n ")" ::: "memory")

#define STAGE(gptr, kb, ldsoff, rs2) do { \
    gload_lds16((gptr) + (kb),         lds + (ldsoff) + tid * 8); \
    gload_lds16((gptr) + (kb) + (rs2), lds + (ldsoff) + 4096 + tid * 8); \
} while (0)

#define RDA(ab, i, kk) (*reinterpret_cast<const bf16x8*>((ab) + (i) * 1024 + ((kk) ? ck1 : ck0)))
#define RDB(bb, j, kk) (*reinterpret_cast<const bf16x8*>((bb) + (j) * 1024 + ((kk) ? ck1 : ck0)))

#define PH_READ_A(ab, ibase) do { \
    _Pragma("unroll") for (int i_ = 0; i_ < 4; ++i_) { \
        a[i_][0] = RDA(ab, (ibase) + i_, 0); \
        a[i_][1] = RDA(ab, (ibase) + i_, 1); } } while (0)
#define PH_READ_B(bb, breg, jbase) do { \
    _Pragma("unroll") for (int j_ = 0; j_ < 2; ++j_) { \
        breg[j_][0] = RDB(bb, (jbase) + j_, 0); \
        breg[j_][1] = RDB(bb, (jbase) + j_, 1); } } while (0)

#define QUAD(IH, BREG, JB) do { \
    __builtin_amdgcn_s_setprio(1); \
    _Pragma("unroll") for (int i_ = 0; i_ < 4; ++i_) \
    _Pragma("unroll") for (int j_ = 0; j_ < 2; ++j_) \
    _Pragma("unroll") for (int k_ = 0; k_ < 2; ++k_) \
        acc[(IH) + i_][(JB) + j_] = __builtin_amdgcn_mfma_f32_16x16x32_bf16( \
            a[i_][k_], BREG[j_][k_], acc[(IH) + i_][(JB) + j_], 0, 0, 0); \
    __builtin_amdgcn_s_setprio(0); \
} while (0)

__global__ __launch_bounds__(512, 2) void gemm_mfma8_kernel(
    const ushort* __restrict__ A2,   // (M, 1024) bf16
    const ushort* __restrict__ B2T,  // (2048 n, 1024 k) bf16
    const float* __restrict__ qk,    // (H, D)
    ushort* __restrict__ v_buf,      // (B, H, T, D) bf16
    float* __restrict__ s_buf)       // (B, H, T)
{
    // LDS: buf0A @0, buf0B @16384, buf1A @32768, buf1B @49152 (ushort units)
    __shared__ ushort lds[65536];          // 128 KB
    __shared__ float spart[8][128];        // 4 KB

    // 256 blocks: xcd = bid&7 owns n-panel; bj = bid>>3 owns m-tiles 2bj,2bj+1
    const int bid = blockIdx.x;
    const int bx  = bid & 7;         // n panel 0..7 (2 heads per panel)
    const int bj  = bid >> 3;        // 0..31
    const int n0  = bx * 256;

    const int tid  = threadIdx.x;
    const int lane = tid & 63;
    const int wid  = tid >> 6;
    const int wr = wid >> 2, wc = wid & 3;
    const int l15 = lane & 15, lg = lane >> 4;

    // staging source addressing (inverse-swizzled global source, linear LDS)
    const int row0 = tid >> 3;
    const int ch0  = (tid & 7) ^ (row0 & 7);
    const ushort* pB  = B2T + (size_t)(n0 + row0) * 1024 + ch0 * 8;
    const ushort* pB1 = pB + 128 * 1024;

    // ds_read addressing (swizzled chunk)
    const int ck0 = ((0 + lg) ^ (l15 & 7)) * 8;
    const int ck1 = ((4 + lg) ^ (l15 & 7)) * 8;
    const ushort* aB0 = lds + (wr * 128 + l15) * 64;
    const ushort* bB0 = lds + 16384 + (wc * 64 + l15) * 64;
    const ushort* aB1 = aB0 + 32768;
    const ushort* bB1 = bB0 + 32768;

    // epilogue constants (same head-panel for both tiles)
    const int h     = 2 * bx + (wc >> 1);
    const int dbase = (wc & 1) * 32 + (l15 >> 1);
    float qv[4];
    #pragma unroll
    for (int j = 0; j < 4; ++j) qv[j] = qk[h * 64 + dbase + j * 8];
    const bool kcol = ((l15 & 1) == 0);

    bf16x8 a[4][2], b01[2][2], b23[2][2];

    // ---- initial prologue for tile 0
    {
        const int m0 = (2 * bj) * 256;
        const ushort* pA  = A2 + (size_t)(m0 + row0) * 1024 + ch0 * 8;
        const ushort* pA1 = pA + 128 * 1024;
        STAGE(pA,  akof(0), 0,             65536);   // Ah1(0)
        STAGE(pA1, akof(0), 8192,          65536);   // Ah2(0)
        STAGE(pB,  bkof(0), 16384,         65536);   // Bh1(0)
        STAGE(pB1, bkof(0), 16384 + 8192,  65536);   // Bh2(0)
        STAGE(pB,  bkof(1), 49152,         65536);   // Bh1(1)
        STAGE(pA,  akof(1), 32768,         65536);   // Ah1(1)
        WAITVM(4);
        BARRIER;
    }

    #pragma unroll 1
    for (int tt = 0; tt < 2; ++tt) {
        const int m0 = (2 * bj + tt) * 256;
        const ushort* pA  = A2 + (size_t)(m0 + row0) * 1024 + ch0 * 8;
        const ushort* pA1 = pA + 128 * 1024;

        f32x4 acc[8][4];
        #pragma unroll
        for (int i = 0; i < 8; ++i)
            #pragma unroll
            for (int j = 0; j < 4; ++j)
                acc[i][j] = (f32x4){0.f, 0.f, 0.f, 0.f};

        // ---- main loop: iteration I computes tiles 2I (buf0), 2I+1 (buf1)
        #pragma unroll 1
        for (int I = 0; I < NT_ / 2 - 1; ++I) {
            const int t1g = 2 * I + 1, t2g = 2 * I + 2, t3g = 2 * I + 3;
            const int ak1 = akof(t1g), bk1 = bkof(t1g);
            const int ak2 = akof(t2g), bk2 = bkof(t2g);
            const int ak3 = akof(t3g), bk3 = bkof(t3g);
            // ph1: Q1(buf0) | stage Ah2(t+1)->buf1
            PH_READ_A(aB0, 0); PH_READ_B(bB0, b01, 0);
            STAGE(pA1, ak1, 32768 + 8192, 65536);
            BARRIER; WAITLGKM; QUAD(0, b01, 0); BARRIER;
            // ph2: Q2(buf0) | stage Bh2(t+1)->buf1
            PH_READ_B(bB0, b23, 2);
            STAGE(pB1, bk1, 49152 + 8192, 65536);
            BARRIER; WAITLGKM; QUAD(0, b23, 2); BARRIER;
            // ph3: Q3(buf0) | stage Bh1(t+2)->buf0
            PH_READ_A(aB0, 4);
            STAGE(pB, bk2, 16384, 65536);
            BARRIER; WAITLGKM; QUAD(4, b01, 0); BARRIER;
            // ph4: Q4(buf0) | stage Ah1(t+2)->buf0; counted vmcnt
            STAGE(pA, ak2, 0, 65536);
            WAITVM(4);
            BARRIER; QUAD(4, b23, 2); BARRIER;
            // ph5: Q1(buf1) | stage Ah2(t+2)->buf0
            PH_READ_A(aB1, 0); PH_READ_B(bB1, b01, 0);
            STAGE(pA1, ak2, 8192, 65536);
            BARRIER; WAITLGKM; QUAD(0, b01, 0); BARRIER;
            // ph6: Q2(buf1) | stage Bh2(t+2)->buf0
            PH_READ_B(bB1, b23, 2);
            STAGE(pB1, bk2, 16384 + 8192, 65536);
            BARRIER; WAITLGKM; QUAD(0, b23, 2); BARRIER;
            // ph7: Q3(buf1) | stage Bh1(t+3)->buf1
            PH_READ_A(aB1, 4);
            STAGE(pB, bk3, 49152, 65536);
            BARRIER; WAITLGKM; QUAD(4, b01, 0); BARRIER;
            // ph8: Q4(buf1) | stage Ah1(t+3)->buf1; counted vmcnt
            STAGE(pA, ak3, 32768, 65536);
            WAITVM(4);
            BARRIER; QUAD(4, b23, 2); BARRIER;
        }

        // ---- epilogue iteration: tiles NT-2 (buf0), NT-1 (buf1); drain
        {
            const int t1g = NT_ - 1;
            const int ak1 = akof(t1g), bk1 = bkof(t1g);
            PH_READ_A(aB0, 0); PH_READ_B(bB0, b01, 0);
            STAGE(pA1, ak1, 32768 + 8192, 65536);     // Ah2(NT-1)
            BARRIER; WAITLGKM; QUAD(0, b01, 0); BARRIER;
            PH_READ_B(bB0, b23, 2);
            STAGE(pB1, bk1, 49152 + 8192, 65536);     // Bh2(NT-1)
            BARRIER; WAITLGKM; QUAD(0, b23, 2); BARRIER;
            PH_READ_A(aB0, 4);
            BARRIER; WAITLGKM; QUAD(4, b01, 0); BARRIER;
            WAITVM(0);
            BARRIER; QUAD(4, b23, 2); BARRIER;
            PH_READ_A(aB1, 0); PH_READ_B(bB1, b01, 0);
            BARRIER; WAITLGKM; QUAD(0, b01, 0); BARRIER;
            PH_READ_B(bB1, b23, 2);
            BARRIER; WAITLGKM; QUAD(0, b23, 2); BARRIER;
            PH_READ_A(aB1, 4);
            BARRIER; WAITLGKM; QUAD(4, b01, 0); BARRIER;
            QUAD(4, b23, 2);
        }

        // All LDS reads of this tile retired before restaging (race-free).
        BARRIER;

        // ---- tile-1 prologue issued here, hidden under tile-0 epilogue.
        if (tt == 0) {
            const int m0n = (2 * bj + 1) * 256;
            const ushort* qA  = A2 + (size_t)(m0n + row0) * 1024 + ch0 * 8;
            const ushort* qA1 = qA + 128 * 1024;
            STAGE(qA,  akof(0), 0,             65536);   // Ah1(0)
            STAGE(qA1, akof(0), 8192,          65536);   // Ah2(0)
            STAGE(pB,  bkof(0), 16384,         65536);   // Bh1(0)
            STAGE(pB1, bkof(0), 16384 + 8192,  65536);   // Bh2(0)
            STAGE(pB,  bkof(1), 49152,         65536);   // Bh1(1)
            STAGE(qA,  akof(1), 32768,         65536);   // Ah1(1)
        }

        // ---- fused epilogue: silu, s-reduction, v store (bf16).
        #pragma unroll
        for (int i = 0; i < 8; ++i) {
            #pragma unroll
            for (int rr = 0; rr < 4; ++rr) {
                int m = m0 + wr * 128 + i * 16 + lg * 4 + rr;
                int b = m >> 12, ttm = m & 4095;
                float p = 0.f;
                #pragma unroll
                for (int j = 0; j < 4; ++j) {
                    float sv = silu_f(acc[i][j][rr]);
                    if (kcol) {
                        p += qv[j] * sv;
                    } else {
                        v_buf[((size_t)(b * H_ + h) * T_ + ttm) * D_ + dbase + j * 8] =
                            f2bf_u(sv);
                    }
                }
                p += __shfl_xor(p, 2);
                p += __shfl_xor(p, 4);
                p += __shfl_xor(p, 8);
                if (l15 == 0) spart[wid][i * 16 + lg * 4 + rr] = p;
            }
        }
        // full drain (vmcnt+lgkmcnt) — tile-1 prefetch has had the whole
        // epilogue to land; this is the only fill-wait tile 1 pays.
        __syncthreads();
        {
            int wr2 = tid >> 8, hl = (tid >> 7) & 1, row = tid & 127;
            int m = m0 + wr2 * 128 + row;
            int b = m >> 12, ttm = m & 4095;
            s_buf[(size_t)(b * H_ + 2 * bx + hl) * T_ + ttm] =
                spart[wr2 * 4 + hl * 2][row] + spart[wr2 * 4 + hl * 2 + 1][row];
        }
        if (tt == 0) {
            // spart fully consumed before tile-1 can overwrite (its first
            // spart write is after its own compute, many barriers away).
            BARRIER;
        }
    }
}

// ---------------------------------------------------------------------------
// Fallback f32 GEMM (round-1) used when ws_size is too small.
// ---------------------------------------------------------------------------
#define TILE_M 128
#define TILE_N 128
#define TILE_K 16
__global__ __launch_bounds__(256) void gemm_kv_kernel(
    const float* __restrict__ A, const float* __restrict__ Bm,
    const float* __restrict__ q, ushort* __restrict__ v_buf,
    float* __restrict__ s_buf)
{
    __shared__ float As[TILE_K][TILE_M + 4];
    __shared__ float Bs[TILE_K][TILE_N + 4];
    const int tid = threadIdx.x;
    const int h   = blockIdx.x;
    const int bm  = blockIdx.y;
    const int m0  = bm * TILE_M;
    const int n0  = h * TILE_N;
    const int tx = tid & 15, ty = tid >> 4;
    float acc[8][8];
    #pragma unroll
    for (int i = 0; i < 8; ++i)
        #pragma unroll
        for (int j = 0; j < 8; ++j) acc[i][j] = 0.f;
    for (int k0 = 0; k0 < I_; k0 += TILE_K) {
        #pragma unroll
        for (int p = 0; p < 2; ++p) {
            int f = tid + p * 256;
            int row = f >> 2, kq = (f & 3) * 4;
            float4 av = *reinterpret_cast<const float4*>(
                &A[(size_t)(m0 + row) * I_ + k0 + kq]);
            As[kq + 0][row] = av.x; As[kq + 1][row] = av.y;
            As[kq + 2][row] = av.z; As[kq + 3][row] = av.w;
        }
        #pragma unroll
        for (int p = 0; p < 2; ++p) {
            int f = tid + p * 256;
            int row = f >> 5, c4 = (f & 31) * 4;
            *reinterpret_cast<float4*>(&Bs[row][c4]) =
                *reinterpret_cast<const float4*>(
                    &Bm[(size_t)(k0 + row) * N_ + n0 + c4]);
        }
        __syncthreads();
        #pragma unroll
        for (int kk = 0; kk < TILE_K; ++kk) {
            float4 a0 = *reinterpret_cast<const float4*>(&As[kk][ty * 8]);
            float4 a1 = *reinterpret_cast<const float4*>(&As[kk][ty * 8 + 4]);
            float4 b0 = *reinterpret_cast<const float4*>(&Bs[kk][tx * 8]);
            float4 b1 = *reinterpret_cast<const float4*>(&Bs[kk][tx * 8 + 4]);
            float af[8] = {a0.x, a0.y, a0.z, a0.w, a1.x, a1.y, a1.z, a1.w};
            float bf[8] = {b0.x, b0.y, b0.z, b0.w, b1.x, b1.y, b1.z, b1.w};
            #pragma unroll
            for (int i = 0; i < 8; ++i)
                #pragma unroll
                for (int j = 0; j < 8; ++j)
                    acc[i][j] = fmaf(af[i], bf[j], acc[i][j]);
        }
        __syncthreads();
    }
    float4 qv = *reinterpret_cast<const float4*>(&q[h * D_ + tx * 4]);
    float qf[4] = {qv.x, qv.y, qv.z, qv.w};
    #pragma unroll
    for (int i = 0; i < 8; ++i) {
        int m = m0 + ty * 8 + i;
        int b = m >> 12, t = m & 4095;
        float partial = 0.f;
        #pragma unroll
        for (int j = 0; j < 4; ++j) {
            float kval = silu_f(acc[i][2 * j]);
            float vv = silu_f(acc[i][2 * j + 1]);
            v_buf[((size_t)(b * H_ + h) * T_ + t) * D_ + tx * 4 + j] = f2bf_u(vv);
            partial = fmaf(qf[j], kval, partial);
        }
        #pragma unroll
        for (int mask = 8; mask >= 1; mask >>= 1)
            partial += __shfl_xor(partial, mask, 16);
        if (tx == 0) s_buf[(size_t)(b * H_ + h) * T_ + t] = partial;
    }
}

// ---------------------------------------------------------------------------
// Scan kernels (v_buf bf16)
// ---------------------------------------------------------------------------
__global__ __launch_bounds__(64) void chunk_agg_kernel(
    const float* __restrict__ s_buf, const ushort* __restrict__ v_buf,
    float* __restrict__ agg_m, float* __restrict__ agg_u,
    float* __restrict__ agg_w)
{
    const int x    = blockIdx.x;
    const int c    = x & (C_ - 1);
    const int bh   = x >> 6;
    const int lane = threadIdx.x;
    const float* sp  = s_buf + (size_t)bh * T_ + c * L_;
    const ushort* vp = v_buf + ((size_t)bh * T_ + c * L_) * D_ + lane;
    float m = -INFINITY, u = 0.f, w = 0.f;
    for (int t = 0; t < L_; ++t) {
        float s  = sp[t];
        float vv = bfu2f(vp[(size_t)t * D_]);
        float mn = fmaxf(m, s);
        float ea = __expf(m - mn);
        float eb = __expf(s - mn);
        u = u * ea + eb;
        w = w * ea + vv * eb;
        m = mn;
    }
    if (lane == 0) { agg_m[x] = m; agg_u[x] = u; }
    agg_w[(size_t)x * D_ + lane] = w;
}

__global__ __launch_bounds__(64) void chunk_prefix_kernel(
    float* __restrict__ agg_m, float* __restrict__ agg_u,
    float* __restrict__ agg_w)
{
    const int bh   = blockIdx.x;
    const int lane = threadIdx.x;
    float pm = -INFINITY, pu = 0.f, pw = 0.f;
    for (int c = 0; c < C_; ++c) {
        int base = bh * C_ + c;
        float am = agg_m[base];
        float au = agg_u[base];
        float aw = agg_w[(size_t)base * D_ + lane];
        if (lane == 0) { agg_m[base] = pm; agg_u[base] = pu; }
        agg_w[(size_t)base * D_ + lane] = pw;
        float mn = fmaxf(pm, am);
        float ea = __expf(pm - mn);
        float eb = __expf(am - mn);
        pu = pu * ea + au * eb;
        pw = pw * ea + aw * eb;
        pm = mn;
    }
}

__global__ __launch_bounds__(256) void scan_apply_kernel(
    const float* __restrict__ s_buf, const ushort* __restrict__ v_buf,
    const float* __restrict__ agg_m, const float* __restrict__ agg_u,
    const float* __restrict__ agg_w, float* __restrict__ out)
{
    __shared__ float part[4][8][64];
    const int bx   = blockIdx.x;
    const int b    = bx >> 6;
    const int c    = bx & (C_ - 1);
    const int w    = threadIdx.x >> 6;
    const int lane = threadIdx.x & 63;
    float m[4], u[4], ws[4];
    #pragma unroll
    for (int j = 0; j < 4; ++j) {
        int h = w * 4 + j;
        int base = (b * H_ + h) * C_ + c;
        m[j]  = agg_m[base];
        u[j]  = agg_u[base];
        ws[j] = agg_w[(size_t)base * D_ + lane];
    }
    const int t0 = c * L_;
    for (int g = 0; g < L_ / 8; ++g) {
        #pragma unroll
        for (int qq = 0; qq < 8; ++qq) {
            int t = t0 + g * 8 + qq;
            float acc = 0.f;
            #pragma unroll
            for (int j = 0; j < 4; ++j) {
                int h = w * 4 + j;
                size_t bht = (size_t)(b * H_ + h) * T_ + t;
                float s  = s_buf[bht];
                float vv = bfu2f(v_buf[bht * D_ + lane]);
                float mn = fmaxf(m[j], s);
                float ea = __expf(m[j] - mn);
                float eb = __expf(s - mn);
                u[j]  = u[j] * ea + eb;
                ws[j] = ws[j] * ea + vv * eb;
                m[j]  = mn;
                acc += ws[j] / u[j];
            }
            part[w][qq][lane] = acc;
        }
        __syncthreads();
        {
            int e  = threadIdx.x;
            int tt = e >> 6, d = e & 63;
            float sum = part[0][tt][d] + part[1][tt][d]
                      + part[2][tt][d] + part[3][tt][d];
            out[((size_t)b * T_ + (t0 + g * 8 + tt)) * D_ + d] = sum * (1.f / 16.f);
        }
        {
            int e  = threadIdx.x + 256;
            int tt = e >> 6, d = e & 63;
            float sum = part[0][tt][d] + part[1][tt][d]
                      + part[2][tt][d] + part[3][tt][d];
            out[((size_t)b * T_ + (t0 + g * 8 + tt)) * D_ + d] = sum * (1.f / 16.f);
        }
        __syncthreads();
    }
}

// ---------------------------------------------------------------------------
extern "C" void kernel_launch(void* const* d_in, const int* in_sizes, int n_in,
                              void* d_out, int out_size, void* d_ws, size_t ws_size,
                              hipStream_t stream) {
    const float* A  = (const float*)d_in[0];  // inputs (B,T,I)
    const float* Bm = (const float*)d_in[1];  // kv_kernel (I,H,D,2)
    const float* q  = (const float*)d_in[2];  // q_kernel (H,D)
    float* out = (float*)d_out;

    // workspace layout: v (bf16) | s | agg_m | agg_u | agg_w | A2 | B2T
    ushort* v_buf = (ushort*)d_ws;                               // 16,777,216 us
    float*  s_buf = (float*)(v_buf + (size_t)B_ * H_ * T_ * D_);
    float*  agg_m = s_buf + (size_t)B_ * H_ * T_;                // 262,144 f
    float*  agg_u = agg_m + B_ * H_ * C_;
    float*  agg_w = agg_u + B_ * H_ * C_;
    ushort* A2    = (ushort*)(agg_w + (size_t)B_ * H_ * C_ * D_);
    ushort* B2T   = A2 + (size_t)M_ * 1024;

    size_t need = (size_t)B_ * H_ * T_ * D_ * 2
                + ((size_t)262144 + 4096 + 4096 + 262144) * 4
                + ((size_t)M_ * 1024 + (size_t)2048 * 1024) * 2;

    if (ws_size >= need) {
        convert_a_kernel<<<M_ * 1024 / (256 * 4), 256, 0, stream>>>(A, A2);
        convert_bT_kernel<<<dim3(16, 32), 256, 0, stream>>>(Bm, B2T);
        gemm_mfma8_kernel<<<256, 512, 0, stream>>>(A2, B2T, q, v_buf, s_buf);
    } else {
        dim3 ggrid(H_, M_ / TILE_M);
        gemm_kv_kernel<<<ggrid, 256, 0, stream>>>(A, Bm, q, v_buf, s_buf);
    }
    chunk_agg_kernel<<<B_ * H_ * C_, 64, 0, stream>>>(s_buf, v_buf, agg_m, agg_u, agg_w);
    chunk_prefix_kernel<<<B_ * H_, 64, 0, stream>>>(agg_m, agg_u, agg_w);
    scan_apply_kernel<<<B_ * C_, 256, 0, stream>>>(s_buf, v_buf, agg_m, agg_u, agg_w, out);
}

// Round 10
// 160.959 us; speedup vs baseline: 1.1935x; 1.0309x over previous
//
#include <hip/hip_runtime.h>
#include <hip/hip_bf16.h>
#include <math.h>

// Problem constants
constexpr int B_ = 4, T_ = 4096, I_ = 1024, H_ = 16, D_ = 64;
constexpr int M_ = B_ * T_;      // 16384 rows  (b*T + t)
constexpr int N_ = H_ * D_ * 2;  // 2048 cols   (h*128 + d*2 + k)
constexpr int C_ = 64;           // scan chunks
constexpr int L_ = T_ / C_;      // 64 timesteps per chunk
constexpr int NT_ = 16;          // K-tiles: plain bf16, K=1024

typedef __bf16 bf16x8 __attribute__((ext_vector_type(8)));
typedef float  f32x4  __attribute__((ext_vector_type(4)));

__device__ __forceinline__ float silu_f(float x) {
    return x / (1.0f + __expf(-x));
}

// bf16 RNE helpers
__device__ __forceinline__ ushort f2bf_u(float x) {
    unsigned u = __float_as_uint(x);
    unsigned r = (u + 0x7fffu + ((u >> 16) & 1u)) >> 16;
    return (ushort)r;
}
__device__ __forceinline__ float bfu2f(ushort u) {
    return __uint_as_float(((unsigned)u) << 16);
}

__device__ __forceinline__ void gload_lds16(const void* g, void* l) {
    __builtin_amdgcn_global_load_lds(
        (const __attribute__((address_space(1))) unsigned int*)g,
        (__attribute__((address_space(3))) unsigned int*)l, 16, 0, 0);
}

// ---------------------------------------------------------------------------
// Fused conversion kernel (one dispatch):
//  blocks [0,16384):   A (M,1024) f32 -> A2 (M,1024) bf16
//  blocks [16384,16896): Bm (1024,2048) f32 -> B2T (2048 n,1024 k) bf16 (T)
// ---------------------------------------------------------------------------
__global__ __launch_bounds__(256) void convert_fused_kernel(
    const float* __restrict__ A,  ushort* __restrict__ A2,
    const float* __restrict__ Bm, ushort* __restrict__ B2T)
{
    __shared__ float tile[64][65];
    const int tid = threadIdx.x;
    if (blockIdx.x < 16384) {
        int idx = blockIdx.x * 256 + tid;
        int m  = idx >> 8;
        int kq = (idx & 255) * 4;
        float4 a = *reinterpret_cast<const float4*>(&A[(size_t)m * 1024 + kq]);
        ushort4 hi;
        hi.x = f2bf_u(a.x);
        hi.y = f2bf_u(a.y);
        hi.z = f2bf_u(a.z);
        hi.w = f2bf_u(a.w);
        *reinterpret_cast<ushort4*>(&A2[(size_t)m * 1024 + kq]) = hi;
    } else {
        int bk = blockIdx.x - 16384;          // 0..511
        const int k0 = (bk & 15) * 64;
        const int n0 = (bk >> 4) * 64;
        #pragma unroll
        for (int p = 0; p < 4; ++p) {
            int f = tid + p * 256;
            int r  = f >> 4;
            int c4 = (f & 15) * 4;
            float4 v = *reinterpret_cast<const float4*>(
                &Bm[(size_t)(k0 + r) * 2048 + n0 + c4]);
            tile[r][c4 + 0] = v.x; tile[r][c4 + 1] = v.y;
            tile[r][c4 + 2] = v.z; tile[r][c4 + 3] = v.w;
        }
        __syncthreads();
        #pragma unroll
        for (int p = 0; p < 4; ++p) {
            int f = tid + p * 256;
            int n  = f >> 4;
            int kq = (f & 15) * 4;
            ushort4 hi;
            hi.x = f2bf_u(tile[kq + 0][n]);
            hi.y = f2bf_u(tile[kq + 1][n]);
            hi.z = f2bf_u(tile[kq + 2][n]);
            hi.w = f2bf_u(tile[kq + 3][n]);
            *reinterpret_cast<ushort4*>(&B2T[(size_t)(n0 + n) * 1024 + k0 + kq]) = hi;
        }
    }
}

// ---------------------------------------------------------------------------
// 256x256 8-phase MFMA GEMM, plain bf16 (K=1024)  [R6 structure], with
// FUSED chunk aggregates: after the K-loop, the dead 128KB staging LDS is
// reused to hold the tile's v (bf16) + s values; 8 waves then compute the
// 8 (chunk,head) scan aggregates in-block (replaces chunk_agg kernel).
// Fused epilogue also does: silu, s = sum_d q*k, v store (bf16).
// 512 threads = 8 waves (2M x 4N); per-wave C = 128x64; BK=64; LDS 128KB dbuf.
// ---------------------------------------------------------------------------
__device__ __forceinline__ int akof(int t) { return t * 64; }
__device__ __forceinline__ int bkof(int t) { return t * 64; }

#define BARRIER do { asm volatile("" ::: "memory"); \
    __builtin_amdgcn_s_barrier(); \
    asm volatile("" ::: "memory"); } while (0)
#define WAITLGKM asm volatile("s_waitcnt lgkmcnt(0)" ::: "memory")
#define WAITVM(n) asm volatile("s_waitcnt vmcnt(" #n ")" ::: "memory")

#define STAGE(gptr, kb, ldsoff, rs2) do { \
    gload_lds16((gptr) + (kb),         lds + (ldsoff) + tid * 8); \
    gload_lds16((gptr) + (kb) + (rs2), lds + (ldsoff) + 4096 + tid * 8); \
} while (0)

#define RDA(ab, i, kk) (*reinterpret_cast<const bf16x8*>((ab) + (i) * 1024 + ((kk) ? ck1 : ck0)))
#define RDB(bb, j, kk) (*reinterpret_cast<const bf16x8*>((bb) + (j) * 1024 + ((kk) ? ck1 : ck0)))

#define PH_READ_A(ab, ibase) do { \
    _Pragma("unroll") for (int i_ = 0; i_ < 4; ++i_) { \
        a[i_][0] = RDA(ab, (ibase) + i_, 0); \
        a[i_][1] = RDA(ab, (ibase) + i_, 1); } } while (0)
#define PH_READ_B(bb, breg, jbase) do { \
    _Pragma("unroll") for (int j_ = 0; j_ < 2; ++j_) { \
        breg[j_][0] = RDB(bb, (jbase) + j_, 0); \
        breg[j_][1] = RDB(bb, (jbase) + j_, 1); } } while (0)

#define QUAD(IH, BREG, JB) do { \
    __builtin_amdgcn_s_setprio(1); \
    _Pragma("unroll") for (int i_ = 0; i_ < 4; ++i_) \
    _Pragma("unroll") for (int j_ = 0; j_ < 2; ++j_) \
    _Pragma("unroll") for (int k_ = 0; k_ < 2; ++k_) \
        acc[(IH) + i_][(JB) + j_] = __builtin_amdgcn_mfma_f32_16x16x32_bf16( \
            a[i_][k_], BREG[j_][k_], acc[(IH) + i_][(JB) + j_], 0, 0, 0); \
    __builtin_amdgcn_s_setprio(0); \
} while (0)

__global__ __launch_bounds__(512, 2) void gemm_mfma8_kernel(
    const ushort* __restrict__ A2,   // (M, 1024) bf16
    const ushort* __restrict__ B2T,  // (2048 n, 1024 k) bf16
    const float* __restrict__ qk,    // (H, D)
    ushort* __restrict__ v_buf,      // (B, H, T, D) bf16
    float* __restrict__ s_buf,       // (B, H, T)
    float* __restrict__ agg_m,       // (B,H,C)
    float* __restrict__ agg_u,       // (B,H,C)
    float* __restrict__ agg_w)       // (B,H,C,D)
{
    // LDS: buf0A @0, buf0B @16384, buf1A @32768, buf1B @49152 (ushort units)
    // After K-loop: reused as v_lds[2 heads][256 t][64 d] (32768 ushorts).
    __shared__ ushort lds[65536];          // 128 KB
    __shared__ float spart[8][128];        // 4 KB
    __shared__ float s_lds[2][256];        // 2 KB

    // XCD swizzle: 512 blocks, 8 XCDs x 64; each XCD owns one n-panel.
    const int bid = blockIdx.x;
    const int swz = (bid & 7) * 64 + (bid >> 3);
    const int bx  = swz >> 6;        // n tile 0..7 (2 heads per tile)
    const int by  = swz & 63;        // m tile 0..63
    const int m0  = by * 256;
    const int n0  = bx * 256;

    const int tid  = threadIdx.x;
    const int lane = tid & 63;
    const int wid  = tid >> 6;
    const int wr = wid >> 2, wc = wid & 3;
    const int l15 = lane & 15, lg = lane >> 4;

    // staging source addressing (inverse-swizzled global source, linear LDS)
    const int row0 = tid >> 3;
    const int ch0  = (tid & 7) ^ (row0 & 7);
    const ushort* pA  = A2  + (size_t)(m0 + row0) * 1024 + ch0 * 8;
    const ushort* pB  = B2T + (size_t)(n0 + row0) * 1024 + ch0 * 8;
    const ushort* pA1 = pA + 128 * 1024;
    const ushort* pB1 = pB + 128 * 1024;

    // ds_read addressing (swizzled chunk)
    const int ck0 = ((0 + lg) ^ (l15 & 7)) * 8;
    const int ck1 = ((4 + lg) ^ (l15 & 7)) * 8;
    const ushort* aB0 = lds + (wr * 128 + l15) * 64;
    const ushort* bB0 = lds + 16384 + (wc * 64 + l15) * 64;
    const ushort* aB1 = aB0 + 32768;
    const ushort* bB1 = bB0 + 32768;

    f32x4 acc[8][4];
    #pragma unroll
    for (int i = 0; i < 8; ++i)
        #pragma unroll
        for (int j = 0; j < 4; ++j)
            acc[i][j] = (f32x4){0.f, 0.f, 0.f, 0.f};
    bf16x8 a[4][2], b01[2][2], b23[2][2];

    // ---- prologue: tile0 (all 4 halves -> buf0), tile1 (Bh1,Ah1 -> buf1)
    {
        STAGE(pA,  akof(0), 0,             65536);   // Ah1(0)
        STAGE(pA1, akof(0), 8192,          65536);   // Ah2(0)
        STAGE(pB,  bkof(0), 16384,         65536);   // Bh1(0)
        STAGE(pB1, bkof(0), 16384 + 8192,  65536);   // Bh2(0)
        STAGE(pB,  bkof(1), 49152,         65536);   // Bh1(1)
        STAGE(pA,  akof(1), 32768,         65536);   // Ah1(1)
        WAITVM(4);
        BARRIER;
    }

    // ---- main loop: iteration I computes tiles 2I (buf0), 2I+1 (buf1)
    #pragma unroll 1
    for (int I = 0; I < NT_ / 2 - 1; ++I) {
        const int t1g = 2 * I + 1, t2g = 2 * I + 2, t3g = 2 * I + 3;
        const int ak1 = akof(t1g), bk1 = bkof(t1g);
        const int ak2 = akof(t2g), bk2 = bkof(t2g);
        const int ak3 = akof(t3g), bk3 = bkof(t3g);
        // ph1: Q1(buf0) | stage Ah2(t+1)->buf1
        PH_READ_A(aB0, 0); PH_READ_B(bB0, b01, 0);
        STAGE(pA1, ak1, 32768 + 8192, 65536);
        BARRIER; WAITLGKM; QUAD(0, b01, 0); BARRIER;
        // ph2: Q2(buf0) | stage Bh2(t+1)->buf1
        PH_READ_B(bB0, b23, 2);
        STAGE(pB1, bk1, 49152 + 8192, 65536);
        BARRIER; WAITLGKM; QUAD(0, b23, 2); BARRIER;
        // ph3: Q3(buf0) | stage Bh1(t+2)->buf0
        PH_READ_A(aB0, 4);
        STAGE(pB, bk2, 16384, 65536);
        BARRIER; WAITLGKM; QUAD(4, b01, 0); BARRIER;
        // ph4: Q4(buf0) | stage Ah1(t+2)->buf0; counted vmcnt
        STAGE(pA, ak2, 0, 65536);
        WAITVM(4);
        BARRIER; QUAD(4, b23, 2); BARRIER;
        // ph5: Q1(buf1) | stage Ah2(t+2)->buf0
        PH_READ_A(aB1, 0); PH_READ_B(bB1, b01, 0);
        STAGE(pA1, ak2, 8192, 65536);
        BARRIER; WAITLGKM; QUAD(0, b01, 0); BARRIER;
        // ph6: Q2(buf1) | stage Bh2(t+2)->buf0
        PH_READ_B(bB1, b23, 2);
        STAGE(pB1, bk2, 16384 + 8192, 65536);
        BARRIER; WAITLGKM; QUAD(0, b23, 2); BARRIER;
        // ph7: Q3(buf1) | stage Bh1(t+3)->buf1
        PH_READ_A(aB1, 4);
        STAGE(pB, bk3, 49152, 65536);
        BARRIER; WAITLGKM; QUAD(4, b01, 0); BARRIER;
        // ph8: Q4(buf1) | stage Ah1(t+3)->buf1; counted vmcnt
        STAGE(pA, ak3, 32768, 65536);
        WAITVM(4);
        BARRIER; QUAD(4, b23, 2); BARRIER;
    }

    // ---- epilogue iteration: tiles NT-2 (buf0), NT-1 (buf1); drain
    {
        const int t1g = NT_ - 1;
        const int ak1 = akof(t1g), bk1 = bkof(t1g);
        PH_READ_A(aB0, 0); PH_READ_B(bB0, b01, 0);
        STAGE(pA1, ak1, 32768 + 8192, 65536);     // Ah2(NT-1)
        BARRIER; WAITLGKM; QUAD(0, b01, 0); BARRIER;
        PH_READ_B(bB0, b23, 2);
        STAGE(pB1, bk1, 49152 + 8192, 65536);     // Bh2(NT-1)
        BARRIER; WAITLGKM; QUAD(0, b23, 2); BARRIER;
        PH_READ_A(aB0, 4);
        BARRIER; WAITLGKM; QUAD(4, b01, 0); BARRIER;
        WAITVM(0);
        BARRIER; QUAD(4, b23, 2); BARRIER;
        PH_READ_A(aB1, 0); PH_READ_B(bB1, b01, 0);
        BARRIER; WAITLGKM; QUAD(0, b01, 0); BARRIER;
        PH_READ_B(bB1, b23, 2);
        BARRIER; WAITLGKM; QUAD(0, b23, 2); BARRIER;
        PH_READ_A(aB1, 4);
        BARRIER; WAITLGKM; QUAD(4, b01, 0); BARRIER;
        QUAD(4, b23, 2);
    }
    // All waves' LDS reads retired before the staging LDS is reused for v.
    BARRIER;

    // ---- fused epilogue: silu, s-reduction, v store (global bf16 + LDS).
    const int hloc  = wc >> 1;
    const int h     = 2 * bx + hloc;
    const int dbase = (wc & 1) * 32 + (l15 >> 1);
    float qv[4];
    #pragma unroll
    for (int j = 0; j < 4; ++j) qv[j] = qk[h * 64 + dbase + j * 8];
    const bool kcol = ((l15 & 1) == 0);

    #pragma unroll
    for (int i = 0; i < 8; ++i) {
        #pragma unroll
        for (int rr = 0; rr < 4; ++rr) {
            int rloc = wr * 128 + i * 16 + lg * 4 + rr;   // 0..255 within tile
            int m = m0 + rloc;
            int b = m >> 12, tt = m & 4095;
            float p = 0.f;
            #pragma unroll
            for (int j = 0; j < 4; ++j) {
                float sv = silu_f(acc[i][j][rr]);
                if (kcol) {
                    p += qv[j] * sv;
                } else {
                    ushort vb = f2bf_u(sv);
                    v_buf[((size_t)(b * H_ + h) * T_ + tt) * D_ + dbase + j * 8] = vb;
                    lds[hloc * 16384 + rloc * 64 + dbase + j * 8] = vb;
                }
            }
            p += __shfl_xor(p, 2);
            p += __shfl_xor(p, 4);
            p += __shfl_xor(p, 8);
            if (l15 == 0) spart[wid][i * 16 + lg * 4 + rr] = p;
        }
    }
    __syncthreads();
    {
        int wr2 = tid >> 8, hl = (tid >> 7) & 1, row = tid & 127;
        int m = m0 + wr2 * 128 + row;
        int b = m >> 12, tt = m & 4095;
        float sval = spart[wr2 * 4 + hl * 2][row] + spart[wr2 * 4 + hl * 2 + 1][row];
        s_buf[(size_t)(b * H_ + 2 * bx + hl) * T_ + tt] = sval;
        s_lds[hl][wr2 * 128 + row] = sval;
    }
    __syncthreads();

    // ---- fused chunk aggregates: 8 waves = 4 chunks x 2 heads.
    {
        const int h_l = wid & 1;
        const int c_l = wid >> 1;
        const int b   = m0 >> 12;
        const int hg  = 2 * bx + h_l;
        const int cg  = ((m0 & 4095) >> 6) + c_l;
        const int base = (b * H_ + hg) * C_ + cg;
        const ushort* vl = lds + h_l * 16384 + (c_l * 64) * 64 + lane;
        const float*  sl = &s_lds[h_l][c_l * 64];
        float m = -INFINITY, u = 0.f, w = 0.f;
        #pragma unroll 8
        for (int t = 0; t < 64; ++t) {
            float s  = sl[t];
            float vv = bfu2f(vl[t * 64]);
            float mn = fmaxf(m, s);
            float ea = __expf(m - mn);
            float eb = __expf(s - mn);
            u = u * ea + eb;
            w = w * ea + vv * eb;
            m = mn;
        }
        if (lane == 0) { agg_m[base] = m; agg_u[base] = u; }
        agg_w[(size_t)base * D_ + lane] = w;
    }
}

// ---------------------------------------------------------------------------
// Fallback f32 GEMM (round-1) used when ws_size is too small.
// ---------------------------------------------------------------------------
#define TILE_M 128
#define TILE_N 128
#define TILE_K 16
__global__ __launch_bounds__(256) void gemm_kv_kernel(
    const float* __restrict__ A, const float* __restrict__ Bm,
    const float* __restrict__ q, ushort* __restrict__ v_buf,
    float* __restrict__ s_buf)
{
    __shared__ float As[TILE_K][TILE_M + 4];
    __shared__ float Bs[TILE_K][TILE_N + 4];
    const int tid = threadIdx.x;
    const int h   = blockIdx.x;
    const int bm  = blockIdx.y;
    const int m0  = bm * TILE_M;
    const int n0  = h * TILE_N;
    const int tx = tid & 15, ty = tid >> 4;
    float acc[8][8];
    #pragma unroll
    for (int i = 0; i < 8; ++i)
        #pragma unroll
        for (int j = 0; j < 8; ++j) acc[i][j] = 0.f;
    for (int k0 = 0; k0 < I_; k0 += TILE_K) {
        #pragma unroll
        for (int p = 0; p < 2; ++p) {
            int f = tid + p * 256;
            int row = f >> 2, kq = (f & 3) * 4;
            float4 av = *reinterpret_cast<const float4*>(
                &A[(size_t)(m0 + row) * I_ + k0 + kq]);
            As[kq + 0][row] = av.x; As[kq + 1][row] = av.y;
            As[kq + 2][row] = av.z; As[kq + 3][row] = av.w;
        }
        #pragma unroll
        for (int p = 0; p < 2; ++p) {
            int f = tid + p * 256;
            int row = f >> 5, c4 = (f & 31) * 4;
            *reinterpret_cast<float4*>(&Bs[row][c4]) =
                *reinterpret_cast<const float4*>(
                    &Bm[(size_t)(k0 + row) * N_ + n0 + c4]);
        }
        __syncthreads();
        #pragma unroll
        for (int kk = 0; kk < TILE_K; ++kk) {
            float4 a0 = *reinterpret_cast<const float4*>(&As[kk][ty * 8]);
            float4 a1 = *reinterpret_cast<const float4*>(&As[kk][ty * 8 + 4]);
            float4 b0 = *reinterpret_cast<const float4*>(&Bs[kk][tx * 8]);
            float4 b1 = *reinterpret_cast<const float4*>(&Bs[kk][tx * 8 + 4]);
            float af[8] = {a0.x, a0.y, a0.z, a0.w, a1.x, a1.y, a1.z, a1.w};
            float bf[8] = {b0.x, b0.y, b0.z, b0.w, b1.x, b1.y, b1.z, b1.w};
            #pragma unroll
            for (int i = 0; i < 8; ++i)
                #pragma unroll
                for (int j = 0; j < 8; ++j)
                    acc[i][j] = fmaf(af[i], bf[j], acc[i][j]);
        }
        __syncthreads();
    }
    float4 qv = *reinterpret_cast<const float4*>(&q[h * D_ + tx * 4]);
    float qf[4] = {qv.x, qv.y, qv.z, qv.w};
    #pragma unroll
    for (int i = 0; i < 8; ++i) {
        int m = m0 + ty * 8 + i;
        int b = m >> 12, t = m & 4095;
        float partial = 0.f;
        #pragma unroll
        for (int j = 0; j < 4; ++j) {
            float kval = silu_f(acc[i][2 * j]);
            float vv = silu_f(acc[i][2 * j + 1]);
            v_buf[((size_t)(b * H_ + h) * T_ + t) * D_ + tx * 4 + j] = f2bf_u(vv);
            partial = fmaf(qf[j], kval, partial);
        }
        #pragma unroll
        for (int mask = 8; mask >= 1; mask >>= 1)
            partial += __shfl_xor(partial, mask, 16);
        if (tx == 0) s_buf[(size_t)(b * H_ + h) * T_ + t] = partial;
    }
}

// ---------------------------------------------------------------------------
// Scan kernels (v_buf bf16). chunk_agg only used on the fallback path.
// ---------------------------------------------------------------------------
__global__ __launch_bounds__(64) void chunk_agg_kernel(
    const float* __restrict__ s_buf, const ushort* __restrict__ v_buf,
    float* __restrict__ agg_m, float* __restrict__ agg_u,
    float* __restrict__ agg_w)
{
    const int x    = blockIdx.x;
    const int c    = x & (C_ - 1);
    const int bh   = x >> 6;
    const int lane = threadIdx.x;
    const float* sp  = s_buf + (size_t)bh * T_ + c * L_;
    const ushort* vp = v_buf + ((size_t)bh * T_ + c * L_) * D_ + lane;
    float m = -INFINITY, u = 0.f, w = 0.f;
    for (int t = 0; t < L_; ++t) {
        float s  = sp[t];
        float vv = bfu2f(vp[(size_t)t * D_]);
        float mn = fmaxf(m, s);
        float ea = __expf(m - mn);
        float eb = __expf(s - mn);
        u = u * ea + eb;
        w = w * ea + vv * eb;
        m = mn;
    }
    if (lane == 0) { agg_m[x] = m; agg_u[x] = u; }
    agg_w[(size_t)x * D_ + lane] = w;
}

__global__ __launch_bounds__(64) void chunk_prefix_kernel(
    float* __restrict__ agg_m, float* __restrict__ agg_u,
    float* __restrict__ agg_w)
{
    const int bh   = blockIdx.x;
    const int lane = threadIdx.x;
    float pm = -INFINITY, pu = 0.f, pw = 0.f;
    #pragma unroll 4
    for (int c = 0; c < C_; ++c) {
        int base = bh * C_ + c;
        float am = agg_m[base];
        float au = agg_u[base];
        float aw = agg_w[(size_t)base * D_ + lane];
        if (lane == 0) { agg_m[base] = pm; agg_u[base] = pu; }
        agg_w[(size_t)base * D_ + lane] = pw;
        float mn = fmaxf(pm, am);
        float ea = __expf(pm - mn);
        float eb = __expf(am - mn);
        pu = pu * ea + au * eb;
        pw = pw * ea + aw * eb;
        pm = mn;
    }
}

__global__ __launch_bounds__(256) void scan_apply_kernel(
    const float* __restrict__ s_buf, const ushort* __restrict__ v_buf,
    const float* __restrict__ agg_m, const float* __restrict__ agg_u,
    const float* __restrict__ agg_w, float* __restrict__ out)
{
    __shared__ float part[4][8][64];
    const int bx   = blockIdx.x;
    const int b    = bx >> 6;
    const int c    = bx & (C_ - 1);
    const int w    = threadIdx.x >> 6;
    const int lane = threadIdx.x & 63;
    float m[4], u[4], ws[4];
    #pragma unroll
    for (int j = 0; j < 4; ++j) {
        int h = w * 4 + j;
        int base = (b * H_ + h) * C_ + c;
        m[j]  = agg_m[base];
        u[j]  = agg_u[base];
        ws[j] = agg_w[(size_t)base * D_ + lane];
    }
    const int t0 = c * L_;
    for (int g = 0; g < L_ / 8; ++g) {
        #pragma unroll
        for (int qq = 0; qq < 8; ++qq) {
            int t = t0 + g * 8 + qq;
            float acc = 0.f;
            #pragma unroll
            for (int j = 0; j < 4; ++j) {
                int h = w * 4 + j;
                size_t bht = (size_t)(b * H_ + h) * T_ + t;
                float s  = s_buf[bht];
                float vv = bfu2f(v_buf[bht * D_ + lane]);
                float mn = fmaxf(m[j], s);
                float ea = __expf(m[j] - mn);
                float eb = __expf(s - mn);
                u[j]  = u[j] * ea + eb;
                ws[j] = ws[j] * ea + vv * eb;
                m[j]  = mn;
                acc += ws[j] / u[j];
            }
            part[w][qq][lane] = acc;
        }
        __syncthreads();
        {
            int e  = threadIdx.x;
            int tt = e >> 6, d = e & 63;
            float sum = part[0][tt][d] + part[1][tt][d]
                      + part[2][tt][d] + part[3][tt][d];
            out[((size_t)b * T_ + (t0 + g * 8 + tt)) * D_ + d] = sum * (1.f / 16.f);
        }
        {
            int e  = threadIdx.x + 256;
            int tt = e >> 6, d = e & 63;
            float sum = part[0][tt][d] + part[1][tt][d]
                      + part[2][tt][d] + part[3][tt][d];
            out[((size_t)b * T_ + (t0 + g * 8 + tt)) * D_ + d] = sum * (1.f / 16.f);
        }
        __syncthreads();
    }
}

// ---------------------------------------------------------------------------
extern "C" void kernel_launch(void* const* d_in, const int* in_sizes, int n_in,
                              void* d_out, int out_size, void* d_ws, size_t ws_size,
                              hipStream_t stream) {
    const float* A  = (const float*)d_in[0];  // inputs (B,T,I)
    const float* Bm = (const float*)d_in[1];  // kv_kernel (I,H,D,2)
    const float* q  = (const float*)d_in[2];  // q_kernel (H,D)
    float* out = (float*)d_out;

    // workspace layout: v (bf16) | s | agg_m | agg_u | agg_w | A2 | B2T
    ushort* v_buf = (ushort*)d_ws;                               // 16,777,216 us
    float*  s_buf = (float*)(v_buf + (size_t)B_ * H_ * T_ * D_);
    float*  agg_m = s_buf + (size_t)B_ * H_ * T_;                // 262,144 f
    float*  agg_u = agg_m + B_ * H_ * C_;
    float*  agg_w = agg_u + B_ * H_ * C_;
    ushort* A2    = (ushort*)(agg_w + (size_t)B_ * H_ * C_ * D_);
    ushort* B2T   = A2 + (size_t)M_ * 1024;

    size_t need = (size_t)B_ * H_ * T_ * D_ * 2
                + ((size_t)262144 + 4096 + 4096 + 262144) * 4
                + ((size_t)M_ * 1024 + (size_t)2048 * 1024) * 2;

    if (ws_size >= need) {
        convert_fused_kernel<<<16896, 256, 0, stream>>>(A, A2, Bm, B2T);
        gemm_mfma8_kernel<<<512, 512, 0, stream>>>(A2, B2T, q, v_buf, s_buf,
                                                   agg_m, agg_u, agg_w);
    } else {
        dim3 ggrid(H_, M_ / TILE_M);
        gemm_kv_kernel<<<ggrid, 256, 0, stream>>>(A, Bm, q, v_buf, s_buf);
        chunk_agg_kernel<<<B_ * H_ * C_, 64, 0, stream>>>(s_buf, v_buf,
                                                          agg_m, agg_u, agg_w);
    }
    chunk_prefix_kernel<<<B_ * H_, 64, 0, stream>>>(agg_m, agg_u, agg_w);
    scan_apply_kernel<<<B_ * C_, 256, 0, stream>>>(s_buf, v_buf, agg_m, agg_u, agg_w, out);
}

// Round 11
// 153.493 us; speedup vs baseline: 1.2516x; 1.0486x over previous
//
#include <hip/hip_runtime.h>
#include <hip/hip_bf16.h>
#include <math.h>

// Problem constants
constexpr int B_ = 4, T_ = 4096, I_ = 1024, H_ = 16, D_ = 64;
constexpr int M_ = B_ * T_;      // 16384 rows  (b*T + t)
constexpr int N_ = H_ * D_ * 2;  // 2048 cols   (h*128 + d*2 + k)
constexpr int C_ = 64;           // scan chunks
constexpr int L_ = T_ / C_;      // 64 timesteps per chunk
constexpr int NT_ = 16;          // K-tiles: plain bf16, K=1024

typedef __bf16 bf16x8 __attribute__((ext_vector_type(8)));
typedef float  f32x4  __attribute__((ext_vector_type(4)));

__device__ __forceinline__ float silu_f(float x) {
    return x / (1.0f + __expf(-x));
}

// bf16 RNE helpers
__device__ __forceinline__ ushort f2bf_u(float x) {
    unsigned u = __float_as_uint(x);
    unsigned r = (u + 0x7fffu + ((u >> 16) & 1u)) >> 16;
    return (ushort)r;
}
__device__ __forceinline__ float bfu2f(ushort u) {
    return __uint_as_float(((unsigned)u) << 16);
}

__device__ __forceinline__ void gload_lds16(const void* g, void* l) {
    __builtin_amdgcn_global_load_lds(
        (const __attribute__((address_space(1))) unsigned int*)g,
        (__attribute__((address_space(3))) unsigned int*)l, 16, 0, 0);
}

// ---------------------------------------------------------------------------
// Fused conversion kernel (one dispatch):
//  blocks [0,16384):   A (M,1024) f32 -> A2 (M,1024) bf16
//  blocks [16384,16896): Bm (1024,2048) f32 -> B2T (2048 n,1024 k) bf16 (T)
// ---------------------------------------------------------------------------
__global__ __launch_bounds__(256) void convert_fused_kernel(
    const float* __restrict__ A,  ushort* __restrict__ A2,
    const float* __restrict__ Bm, ushort* __restrict__ B2T)
{
    __shared__ float tile[64][65];
    const int tid = threadIdx.x;
    if (blockIdx.x < 16384) {
        int idx = blockIdx.x * 256 + tid;
        int m  = idx >> 8;
        int kq = (idx & 255) * 4;
        float4 a = *reinterpret_cast<const float4*>(&A[(size_t)m * 1024 + kq]);
        ushort4 hi;
        hi.x = f2bf_u(a.x);
        hi.y = f2bf_u(a.y);
        hi.z = f2bf_u(a.z);
        hi.w = f2bf_u(a.w);
        *reinterpret_cast<ushort4*>(&A2[(size_t)m * 1024 + kq]) = hi;
    } else {
        int bk = blockIdx.x - 16384;          // 0..511
        const int k0 = (bk & 15) * 64;
        const int n0 = (bk >> 4) * 64;
        #pragma unroll
        for (int p = 0; p < 4; ++p) {
            int f = tid + p * 256;
            int r  = f >> 4;
            int c4 = (f & 15) * 4;
            float4 v = *reinterpret_cast<const float4*>(
                &Bm[(size_t)(k0 + r) * 2048 + n0 + c4]);
            tile[r][c4 + 0] = v.x; tile[r][c4 + 1] = v.y;
            tile[r][c4 + 2] = v.z; tile[r][c4 + 3] = v.w;
        }
        __syncthreads();
        #pragma unroll
        for (int p = 0; p < 4; ++p) {
            int f = tid + p * 256;
            int n  = f >> 4;
            int kq = (f & 15) * 4;
            ushort4 hi;
            hi.x = f2bf_u(tile[kq + 0][n]);
            hi.y = f2bf_u(tile[kq + 1][n]);
            hi.z = f2bf_u(tile[kq + 2][n]);
            hi.w = f2bf_u(tile[kq + 3][n]);
            *reinterpret_cast<ushort4*>(&B2T[(size_t)(n0 + n) * 1024 + k0 + kq]) = hi;
        }
    }
}

// ---------------------------------------------------------------------------
// 256x256 8-phase MFMA GEMM, plain bf16 (K=1024), with IN-REGISTER fused
// chunk aggregates: after the K-loop, each wave aggregates its own chunk rows
// from the still-live acc (silu recomputed), s from LDS broadcast; cross-lg
// combine via shfl_xor butterfly (the online-softmax combine is a commutative
// associative monoid, so any combine order is valid).
// Fused epilogue also does: silu, s = sum_d q*k, v store (bf16).
// 512 threads = 8 waves (2M x 4N); per-wave C = 128x64; BK=64; LDS 128KB dbuf.
// ---------------------------------------------------------------------------
__device__ __forceinline__ int akof(int t) { return t * 64; }
__device__ __forceinline__ int bkof(int t) { return t * 64; }

#define BARRIER do { asm volatile("" ::: "memory"); \
    __builtin_amdgcn_s_barrier(); \
    asm volatile("" ::: "memory"); } while (0)
#define WAITLGKM asm volatile("s_waitcnt lgkmcnt(0)" ::: "memory")
#define WAITVM(n) asm volatile("s_waitcnt vmcnt(" #n ")" ::: "memory")

#define STAGE(gptr, kb, ldsoff, rs2) do { \
    gload_lds16((gptr) + (kb),         lds + (ldsoff) + tid * 8); \
    gload_lds16((gptr) + (kb) + (rs2), lds + (ldsoff) + 4096 + tid * 8); \
} while (0)

#define RDA(ab, i, kk) (*reinterpret_cast<const bf16x8*>((ab) + (i) * 1024 + ((kk) ? ck1 : ck0)))
#define RDB(bb, j, kk) (*reinterpret_cast<const bf16x8*>((bb) + (j) * 1024 + ((kk) ? ck1 : ck0)))

#define PH_READ_A(ab, ibase) do { \
    _Pragma("unroll") for (int i_ = 0; i_ < 4; ++i_) { \
        a[i_][0] = RDA(ab, (ibase) + i_, 0); \
        a[i_][1] = RDA(ab, (ibase) + i_, 1); } } while (0)
#define PH_READ_B(bb, breg, jbase) do { \
    _Pragma("unroll") for (int j_ = 0; j_ < 2; ++j_) { \
        breg[j_][0] = RDB(bb, (jbase) + j_, 0); \
        breg[j_][1] = RDB(bb, (jbase) + j_, 1); } } while (0)

#define QUAD(IH, BREG, JB) do { \
    __builtin_amdgcn_s_setprio(1); \
    _Pragma("unroll") for (int i_ = 0; i_ < 4; ++i_) \
    _Pragma("unroll") for (int j_ = 0; j_ < 2; ++j_) \
    _Pragma("unroll") for (int k_ = 0; k_ < 2; ++k_) \
        acc[(IH) + i_][(JB) + j_] = __builtin_amdgcn_mfma_f32_16x16x32_bf16( \
            a[i_][k_], BREG[j_][k_], acc[(IH) + i_][(JB) + j_], 0, 0, 0); \
    __builtin_amdgcn_s_setprio(0); \
} while (0)

__global__ __launch_bounds__(512, 2) void gemm_mfma8_kernel(
    const ushort* __restrict__ A2,   // (M, 1024) bf16
    const ushort* __restrict__ B2T,  // (2048 n, 1024 k) bf16
    const float* __restrict__ qk,    // (H, D)
    ushort* __restrict__ v_buf,      // (B, H, T, D) bf16
    float* __restrict__ s_buf,       // (B, H, T)
    float* __restrict__ agg_m,       // (B,H,C)
    float* __restrict__ agg_u,       // (B,H,C)
    float* __restrict__ agg_w)       // (B,H,C,D)
{
    // LDS: buf0A @0, buf0B @16384, buf1A @32768, buf1B @49152 (ushort units)
    __shared__ ushort lds[65536];          // 128 KB
    __shared__ float spart[8][128];        // 4 KB
    __shared__ float s_lds[2][256];        // 2 KB

    // XCD swizzle: 512 blocks, 8 XCDs x 64; each XCD owns one n-panel.
    const int bid = blockIdx.x;
    const int swz = (bid & 7) * 64 + (bid >> 3);
    const int bx  = swz >> 6;        // n tile 0..7 (2 heads per tile)
    const int by  = swz & 63;        // m tile 0..63
    const int m0  = by * 256;
    const int n0  = bx * 256;

    const int tid  = threadIdx.x;
    const int lane = tid & 63;
    const int wid  = tid >> 6;
    const int wr = wid >> 2, wc = wid & 3;
    const int l15 = lane & 15, lg = lane >> 4;

    // staging source addressing (inverse-swizzled global source, linear LDS)
    const int row0 = tid >> 3;
    const int ch0  = (tid & 7) ^ (row0 & 7);
    const ushort* pA  = A2  + (size_t)(m0 + row0) * 1024 + ch0 * 8;
    const ushort* pB  = B2T + (size_t)(n0 + row0) * 1024 + ch0 * 8;
    const ushort* pA1 = pA + 128 * 1024;
    const ushort* pB1 = pB + 128 * 1024;

    // ds_read addressing (swizzled chunk)
    const int ck0 = ((0 + lg) ^ (l15 & 7)) * 8;
    const int ck1 = ((4 + lg) ^ (l15 & 7)) * 8;
    const ushort* aB0 = lds + (wr * 128 + l15) * 64;
    const ushort* bB0 = lds + 16384 + (wc * 64 + l15) * 64;
    const ushort* aB1 = aB0 + 32768;
    const ushort* bB1 = bB0 + 32768;

    f32x4 acc[8][4];
    #pragma unroll
    for (int i = 0; i < 8; ++i)
        #pragma unroll
        for (int j = 0; j < 4; ++j)
            acc[i][j] = (f32x4){0.f, 0.f, 0.f, 0.f};
    bf16x8 a[4][2], b01[2][2], b23[2][2];

    // ---- prologue: tile0 (all 4 halves -> buf0), tile1 (Bh1,Ah1 -> buf1)
    {
        STAGE(pA,  akof(0), 0,             65536);   // Ah1(0)
        STAGE(pA1, akof(0), 8192,          65536);   // Ah2(0)
        STAGE(pB,  bkof(0), 16384,         65536);   // Bh1(0)
        STAGE(pB1, bkof(0), 16384 + 8192,  65536);   // Bh2(0)
        STAGE(pB,  bkof(1), 49152,         65536);   // Bh1(1)
        STAGE(pA,  akof(1), 32768,         65536);   // Ah1(1)
        WAITVM(4);
        BARRIER;
    }

    // ---- main loop: iteration I computes tiles 2I (buf0), 2I+1 (buf1)
    #pragma unroll 1
    for (int I = 0; I < NT_ / 2 - 1; ++I) {
        const int t1g = 2 * I + 1, t2g = 2 * I + 2, t3g = 2 * I + 3;
        const int ak1 = akof(t1g), bk1 = bkof(t1g);
        const int ak2 = akof(t2g), bk2 = bkof(t2g);
        const int ak3 = akof(t3g), bk3 = bkof(t3g);
        // ph1: Q1(buf0) | stage Ah2(t+1)->buf1
        PH_READ_A(aB0, 0); PH_READ_B(bB0, b01, 0);
        STAGE(pA1, ak1, 32768 + 8192, 65536);
        BARRIER; WAITLGKM; QUAD(0, b01, 0); BARRIER;
        // ph2: Q2(buf0) | stage Bh2(t+1)->buf1
        PH_READ_B(bB0, b23, 2);
        STAGE(pB1, bk1, 49152 + 8192, 65536);
        BARRIER; WAITLGKM; QUAD(0, b23, 2); BARRIER;
        // ph3: Q3(buf0) | stage Bh1(t+2)->buf0
        PH_READ_A(aB0, 4);
        STAGE(pB, bk2, 16384, 65536);
        BARRIER; WAITLGKM; QUAD(4, b01, 0); BARRIER;
        // ph4: Q4(buf0) | stage Ah1(t+2)->buf0; counted vmcnt
        STAGE(pA, ak2, 0, 65536);
        WAITVM(4);
        BARRIER; QUAD(4, b23, 2); BARRIER;
        // ph5: Q1(buf1) | stage Ah2(t+2)->buf0
        PH_READ_A(aB1, 0); PH_READ_B(bB1, b01, 0);
        STAGE(pA1, ak2, 8192, 65536);
        BARRIER; WAITLGKM; QUAD(0, b01, 0); BARRIER;
        // ph6: Q2(buf1) | stage Bh2(t+2)->buf0
        PH_READ_B(bB1, b23, 2);
        STAGE(pB1, bk2, 16384 + 8192, 65536);
        BARRIER; WAITLGKM; QUAD(0, b23, 2); BARRIER;
        // ph7: Q3(buf1) | stage Bh1(t+3)->buf1
        PH_READ_A(aB1, 4);
        STAGE(pB, bk3, 49152, 65536);
        BARRIER; WAITLGKM; QUAD(4, b01, 0); BARRIER;
        // ph8: Q4(buf1) | stage Ah1(t+3)->buf1; counted vmcnt
        STAGE(pA, ak3, 32768, 65536);
        WAITVM(4);
        BARRIER; QUAD(4, b23, 2); BARRIER;
    }

    // ---- epilogue iteration: tiles NT-2 (buf0), NT-1 (buf1); drain
    {
        const int t1g = NT_ - 1;
        const int ak1 = akof(t1g), bk1 = bkof(t1g);
        PH_READ_A(aB0, 0); PH_READ_B(bB0, b01, 0);
        STAGE(pA1, ak1, 32768 + 8192, 65536);     // Ah2(NT-1)
        BARRIER; WAITLGKM; QUAD(0, b01, 0); BARRIER;
        PH_READ_B(bB0, b23, 2);
        STAGE(pB1, bk1, 49152 + 8192, 65536);     // Bh2(NT-1)
        BARRIER; WAITLGKM; QUAD(0, b23, 2); BARRIER;
        PH_READ_A(aB0, 4);
        BARRIER; WAITLGKM; QUAD(4, b01, 0); BARRIER;
        WAITVM(0);
        BARRIER; QUAD(4, b23, 2); BARRIER;
        PH_READ_A(aB1, 0); PH_READ_B(bB1, b01, 0);
        BARRIER; WAITLGKM; QUAD(0, b01, 0); BARRIER;
        PH_READ_B(bB1, b23, 2);
        BARRIER; WAITLGKM; QUAD(0, b23, 2); BARRIER;
        PH_READ_A(aB1, 4);
        BARRIER; WAITLGKM; QUAD(4, b01, 0); BARRIER;
        QUAD(4, b23, 2);
    }

    // ---- fused epilogue: silu, s-reduction, v store (bf16).
    const int hloc  = wc >> 1;
    const int h     = 2 * bx + hloc;
    const int dbase = (wc & 1) * 32 + (l15 >> 1);
    float qv[4];
    #pragma unroll
    for (int j = 0; j < 4; ++j) qv[j] = qk[h * 64 + dbase + j * 8];
    const bool kcol = ((l15 & 1) == 0);

    #pragma unroll
    for (int i = 0; i < 8; ++i) {
        #pragma unroll
        for (int rr = 0; rr < 4; ++rr) {
            int rloc = wr * 128 + i * 16 + lg * 4 + rr;   // 0..255 within tile
            int m = m0 + rloc;
            int b = m >> 12, tt = m & 4095;
            float p = 0.f;
            #pragma unroll
            for (int j = 0; j < 4; ++j) {
                float sv = silu_f(acc[i][j][rr]);
                if (kcol) {
                    p += qv[j] * sv;
                } else {
                    v_buf[((size_t)(b * H_ + h) * T_ + tt) * D_ + dbase + j * 8] =
                        f2bf_u(sv);
                }
            }
            p += __shfl_xor(p, 2);
            p += __shfl_xor(p, 4);
            p += __shfl_xor(p, 8);
            if (l15 == 0) spart[wid][i * 16 + lg * 4 + rr] = p;
        }
    }
    __syncthreads();
    {
        int wr2 = tid >> 8, hl = (tid >> 7) & 1, row = tid & 127;
        int m = m0 + wr2 * 128 + row;
        int b = m >> 12, tt = m & 4095;
        float sval = spart[wr2 * 4 + hl * 2][row] + spart[wr2 * 4 + hl * 2 + 1][row];
        s_buf[(size_t)(b * H_ + 2 * bx + hl) * T_ + tt] = sval;
        s_lds[hl][wr2 * 128 + row] = sval;
    }
    __syncthreads();

    // ---- in-register fused chunk aggregates.
    // Wave (wr,wc) owns chunks c_l = 2wr, 2wr+1 (its acc rows); head hloc,
    // d-half wc&1. Lane aggregates its 16 rows/chunk (combine is a
    // commutative monoid -> any order); shfl_xor(16/32) combines across lg
    // (partner lanes hold the same d columns).
    {
        const int b  = m0 >> 12;
        #pragma unroll
        for (int cc = 0; cc < 2; ++cc) {
            const int c_l = wr * 2 + cc;
            const int cg  = ((m0 & 4095) >> 6) + c_l;
            float mm = -INFINITY, u = 0.f;
            float w0 = 0.f, w1 = 0.f, w2 = 0.f, w3 = 0.f;
            #pragma unroll
            for (int ir = 0; ir < 4; ++ir) {
                #pragma unroll
                for (int rr = 0; rr < 4; ++rr) {
                    float s  = s_lds[hloc][c_l * 64 + ir * 16 + lg * 4 + rr];
                    float mn = fmaxf(mm, s);
                    float ea = __expf(mm - mn);
                    float eb = __expf(s - mn);
                    u  = u * ea + eb;
                    w0 = w0 * ea + silu_f(acc[cc * 4 + ir][0][rr]) * eb;
                    w1 = w1 * ea + silu_f(acc[cc * 4 + ir][1][rr]) * eb;
                    w2 = w2 * ea + silu_f(acc[cc * 4 + ir][2][rr]) * eb;
                    w3 = w3 * ea + silu_f(acc[cc * 4 + ir][3][rr]) * eb;
                    mm = mn;
                }
            }
            #pragma unroll
            for (int mk = 16; mk <= 32; mk <<= 1) {
                float om = __shfl_xor(mm, mk);
                float ou = __shfl_xor(u,  mk);
                float o0 = __shfl_xor(w0, mk);
                float o1 = __shfl_xor(w1, mk);
                float o2 = __shfl_xor(w2, mk);
                float o3 = __shfl_xor(w3, mk);
                float mn = fmaxf(mm, om);
                float ea = __expf(mm - mn);
                float eb = __expf(om - mn);
                u  = u * ea + ou * eb;
                w0 = w0 * ea + o0 * eb;
                w1 = w1 * ea + o1 * eb;
                w2 = w2 * ea + o2 * eb;
                w3 = w3 * ea + o3 * eb;
                mm = mn;
            }
            const int base = (b * H_ + h) * C_ + cg;
            if ((wc & 1) == 0 && lane == 0) {
                agg_m[base] = mm;
                agg_u[base] = u;
            }
            if (!kcol && lg == 0) {
                agg_w[(size_t)base * D_ + dbase + 0 ] = w0;
                agg_w[(size_t)base * D_ + dbase + 8 ] = w1;
                agg_w[(size_t)base * D_ + dbase + 16] = w2;
                agg_w[(size_t)base * D_ + dbase + 24] = w3;
            }
        }
    }
}

// ---------------------------------------------------------------------------
// Fallback f32 GEMM (round-1) used when ws_size is too small.
// ---------------------------------------------------------------------------
#define TILE_M 128
#define TILE_N 128
#define TILE_K 16
__global__ __launch_bounds__(256) void gemm_kv_kernel(
    const float* __restrict__ A, const float* __restrict__ Bm,
    const float* __restrict__ q, ushort* __restrict__ v_buf,
    float* __restrict__ s_buf)
{
    __shared__ float As[TILE_K][TILE_M + 4];
    __shared__ float Bs[TILE_K][TILE_N + 4];
    const int tid = threadIdx.x;
    const int h   = blockIdx.x;
    const int bm  = blockIdx.y;
    const int m0  = bm * TILE_M;
    const int n0  = h * TILE_N;
    const int tx = tid & 15, ty = tid >> 4;
    float acc[8][8];
    #pragma unroll
    for (int i = 0; i < 8; ++i)
        #pragma unroll
        for (int j = 0; j < 8; ++j) acc[i][j] = 0.f;
    for (int k0 = 0; k0 < I_; k0 += TILE_K) {
        #pragma unroll
        for (int p = 0; p < 2; ++p) {
            int f = tid + p * 256;
            int row = f >> 2, kq = (f & 3) * 4;
            float4 av = *reinterpret_cast<const float4*>(
                &A[(size_t)(m0 + row) * I_ + k0 + kq]);
            As[kq + 0][row] = av.x; As[kq + 1][row] = av.y;
            As[kq + 2][row] = av.z; As[kq + 3][row] = av.w;
        }
        #pragma unroll
        for (int p = 0; p < 2; ++p) {
            int f = tid + p * 256;
            int row = f >> 5, c4 = (f & 31) * 4;
            *reinterpret_cast<float4*>(&Bs[row][c4]) =
                *reinterpret_cast<const float4*>(
                    &Bm[(size_t)(k0 + row) * N_ + n0 + c4]);
        }
        __syncthreads();
        #pragma unroll
        for (int kk = 0; kk < TILE_K; ++kk) {
            float4 a0 = *reinterpret_cast<const float4*>(&As[kk][ty * 8]);
            float4 a1 = *reinterpret_cast<const float4*>(&As[kk][ty * 8 + 4]);
            float4 b0 = *reinterpret_cast<const float4*>(&Bs[kk][tx * 8]);
            float4 b1 = *reinterpret_cast<const float4*>(&Bs[kk][tx * 8 + 4]);
            float af[8] = {a0.x, a0.y, a0.z, a0.w, a1.x, a1.y, a1.z, a1.w};
            float bf[8] = {b0.x, b0.y, b0.z, b0.w, b1.x, b1.y, b1.z, b1.w};
            #pragma unroll
            for (int i = 0; i < 8; ++i)
                #pragma unroll
                for (int j = 0; j < 8; ++j)
                    acc[i][j] = fmaf(af[i], bf[j], acc[i][j]);
        }
        __syncthreads();
    }
    float4 qv = *reinterpret_cast<const float4*>(&q[h * D_ + tx * 4]);
    float qf[4] = {qv.x, qv.y, qv.z, qv.w};
    #pragma unroll
    for (int i = 0; i < 8; ++i) {
        int m = m0 + ty * 8 + i;
        int b = m >> 12, t = m & 4095;
        float partial = 0.f;
        #pragma unroll
        for (int j = 0; j < 4; ++j) {
            float kval = silu_f(acc[i][2 * j]);
            float vv = silu_f(acc[i][2 * j + 1]);
            v_buf[((size_t)(b * H_ + h) * T_ + t) * D_ + tx * 4 + j] = f2bf_u(vv);
            partial = fmaf(qf[j], kval, partial);
        }
        #pragma unroll
        for (int mask = 8; mask >= 1; mask >>= 1)
            partial += __shfl_xor(partial, mask, 16);
        if (tx == 0) s_buf[(size_t)(b * H_ + h) * T_ + t] = partial;
    }
}

// ---------------------------------------------------------------------------
// Scan kernels (v_buf bf16). chunk_agg only used on the fallback path.
// ---------------------------------------------------------------------------
__global__ __launch_bounds__(64) void chunk_agg_kernel(
    const float* __restrict__ s_buf, const ushort* __restrict__ v_buf,
    float* __restrict__ agg_m, float* __restrict__ agg_u,
    float* __restrict__ agg_w)
{
    const int x    = blockIdx.x;
    const int c    = x & (C_ - 1);
    const int bh   = x >> 6;
    const int lane = threadIdx.x;
    const float* sp  = s_buf + (size_t)bh * T_ + c * L_;
    const ushort* vp = v_buf + ((size_t)bh * T_ + c * L_) * D_ + lane;
    float m = -INFINITY, u = 0.f, w = 0.f;
    for (int t = 0; t < L_; ++t) {
        float s  = sp[t];
        float vv = bfu2f(vp[(size_t)t * D_]);
        float mn = fmaxf(m, s);
        float ea = __expf(m - mn);
        float eb = __expf(s - mn);
        u = u * ea + eb;
        w = w * ea + vv * eb;
        m = mn;
    }
    if (lane == 0) { agg_m[x] = m; agg_u[x] = u; }
    agg_w[(size_t)x * D_ + lane] = w;
}

__global__ __launch_bounds__(64) void chunk_prefix_kernel(
    float* __restrict__ agg_m, float* __restrict__ agg_u,
    float* __restrict__ agg_w)
{
    const int bh   = blockIdx.x;
    const int lane = threadIdx.x;
    float pm = -INFINITY, pu = 0.f, pw = 0.f;
    #pragma unroll 4
    for (int c = 0; c < C_; ++c) {
        int base = bh * C_ + c;
        float am = agg_m[base];
        float au = agg_u[base];
        float aw = agg_w[(size_t)base * D_ + lane];
        if (lane == 0) { agg_m[base] = pm; agg_u[base] = pu; }
        agg_w[(size_t)base * D_ + lane] = pw;
        float mn = fmaxf(pm, am);
        float ea = __expf(pm - mn);
        float eb = __expf(am - mn);
        pu = pu * ea + au * eb;
        pw = pw * ea + aw * eb;
        pm = mn;
    }
}

__global__ __launch_bounds__(256) void scan_apply_kernel(
    const float* __restrict__ s_buf, const ushort* __restrict__ v_buf,
    const float* __restrict__ agg_m, const float* __restrict__ agg_u,
    const float* __restrict__ agg_w, float* __restrict__ out)
{
    __shared__ float part[4][8][64];
    const int bx   = blockIdx.x;
    const int b    = bx >> 6;
    const int c    = bx & (C_ - 1);
    const int w    = threadIdx.x >> 6;
    const int lane = threadIdx.x & 63;
    float m[4], u[4], ws[4];
    #pragma unroll
    for (int j = 0; j < 4; ++j) {
        int h = w * 4 + j;
        int base = (b * H_ + h) * C_ + c;
        m[j]  = agg_m[base];
        u[j]  = agg_u[base];
        ws[j] = agg_w[(size_t)base * D_ + lane];
    }
    const int t0 = c * L_;
    for (int g = 0; g < L_ / 8; ++g) {
        #pragma unroll
        for (int qq = 0; qq < 8; ++qq) {
            int t = t0 + g * 8 + qq;
            float acc = 0.f;
            #pragma unroll
            for (int j = 0; j < 4; ++j) {
                int h = w * 4 + j;
                size_t bht = (size_t)(b * H_ + h) * T_ + t;
                float s  = s_buf[bht];
                float vv = bfu2f(v_buf[bht * D_ + lane]);
                float mn = fmaxf(m[j], s);
                float ea = __expf(m[j] - mn);
                float eb = __expf(s - mn);
                u[j]  = u[j] * ea + eb;
                ws[j] = ws[j] * ea + vv * eb;
                m[j]  = mn;
                acc += ws[j] / u[j];
            }
            part[w][qq][lane] = acc;
        }
        __syncthreads();
        {
            int e  = threadIdx.x;
            int tt = e >> 6, d = e & 63;
            float sum = part[0][tt][d] + part[1][tt][d]
                      + part[2][tt][d] + part[3][tt][d];
            out[((size_t)b * T_ + (t0 + g * 8 + tt)) * D_ + d] = sum * (1.f / 16.f);
        }
        {
            int e  = threadIdx.x + 256;
            int tt = e >> 6, d = e & 63;
            float sum = part[0][tt][d] + part[1][tt][d]
                      + part[2][tt][d] + part[3][tt][d];
            out[((size_t)b * T_ + (t0 + g * 8 + tt)) * D_ + d] = sum * (1.f / 16.f);
        }
        __syncthreads();
    }
}

// ---------------------------------------------------------------------------
extern "C" void kernel_launch(void* const* d_in, const int* in_sizes, int n_in,
                              void* d_out, int out_size, void* d_ws, size_t ws_size,
                              hipStream_t stream) {
    const float* A  = (const float*)d_in[0];  // inputs (B,T,I)
    const float* Bm = (const float*)d_in[1];  // kv_kernel (I,H,D,2)
    const float* q  = (const float*)d_in[2];  // q_kernel (H,D)
    float* out = (float*)d_out;

    // workspace layout: v (bf16) | s | agg_m | agg_u | agg_w | A2 | B2T
    ushort* v_buf = (ushort*)d_ws;                               // 16,777,216 us
    float*  s_buf = (float*)(v_buf + (size_t)B_ * H_ * T_ * D_);
    float*  agg_m = s_buf + (size_t)B_ * H_ * T_;                // 262,144 f
    float*  agg_u = agg_m + B_ * H_ * C_;
    float*  agg_w = agg_u + B_ * H_ * C_;
    ushort* A2    = (ushort*)(agg_w + (size_t)B_ * H_ * C_ * D_);
    ushort* B2T   = A2 + (size_t)M_ * 1024;

    size_t need = (size_t)B_ * H_ * T_ * D_ * 2
                + ((size_t)262144 + 4096 + 4096 + 262144) * 4
                + ((size_t)M_ * 1024 + (size_t)2048 * 1024) * 2;

    if (ws_size >= need) {
        convert_fused_kernel<<<16896, 256, 0, stream>>>(A, A2, Bm, B2T);
        gemm_mfma8_kernel<<<512, 512, 0, stream>>>(A2, B2T, q, v_buf, s_buf,
                                                   agg_m, agg_u, agg_w);
    } else {
        dim3 ggrid(H_, M_ / TILE_M);
        gemm_kv_kernel<<<ggrid, 256, 0, stream>>>(A, Bm, q, v_buf, s_buf);
        chunk_agg_kernel<<<B_ * H_ * C_, 64, 0, stream>>>(s_buf, v_buf,
                                                          agg_m, agg_u, agg_w);
    }
    chunk_prefix_kernel<<<B_ * H_, 64, 0, stream>>>(agg_m, agg_u, agg_w);
    scan_apply_kernel<<<B_ * C_, 256, 0, stream>>>(s_buf, v_buf, agg_m, agg_u, agg_w, out);
}